// Round 1
// baseline (1427.323 us; speedup 1.0000x reference)
//
#include <hip/hip_runtime.h>

#define F_IN 128
#define DIM_H 256
#define N_CLASSES 40
#define BN_EPS 1e-5f

// ---------------- scatter: agg[dst] += x[src] ----------------
// 32 threads per edge, 4 channels each (float4 gather, 4 scalar atomics).
__global__ void scatter_kernel(const float* __restrict__ x,
                               const int* __restrict__ src,
                               const int* __restrict__ dst,
                               float* __restrict__ agg, int nE, int M) {
    int gid = blockIdx.x * blockDim.x + threadIdx.x;
    int e = gid >> 5;
    if (e >= nE) return;
    int c = (gid & 31) << 2;
    int s = src[e], d = dst[e];
    if ((unsigned)s >= (unsigned)M || (unsigned)d >= (unsigned)M) return;  // safety
    const float4 v = *(const float4*)(x + (long)s * F_IN + c);
    float* p = agg + (long)d * F_IN + c;
    atomicAdd(p + 0, v.x);
    atomicAdd(p + 1, v.y);
    atomicAdd(p + 2, v.z);
    atomicAdd(p + 3, v.w);
}

// ---------------- BN statistics ----------------
// Each block: contiguous row range, per-thread column accumulation (coalesced:
// 256 threads read one full 256-wide row per step). Then atomic per-channel.
__global__ void bn_stats_kernel(const float* __restrict__ h1,
                                float* __restrict__ stats, int M) {
    int c = threadIdx.x;  // 0..255
    int rows_per_block = (M + gridDim.x - 1) / gridDim.x;
    int r0 = blockIdx.x * rows_per_block;
    int r1 = min(M, r0 + rows_per_block);
    float s = 0.f, ss = 0.f;
    for (int r = r0; r < r1; ++r) {
        float v = h1[(long)r * DIM_H + c];
        s += v;
        ss += v * v;
    }
    atomicAdd(&stats[c], s);
    atomicAdd(&stats[DIM_H + c], ss);
}

__global__ void bn_finalize_kernel(const float* __restrict__ stats,
                                   const float* __restrict__ gamma,
                                   const float* __restrict__ beta,
                                   float* __restrict__ scale,
                                   float* __restrict__ shift, int M) {
    int c = threadIdx.x;
    float inv_m = 1.0f / (float)M;
    float mean = stats[c] * inv_m;
    float var = stats[DIM_H + c] * inv_m - mean * mean;
    float sc = gamma[c] * rsqrtf(var + BN_EPS);
    scale[c] = sc;
    shift[c] = beta[c] - mean * sc;
}

// ---------------- GEMM: C[M,N] = op(A[M,K]) @ B[K,N] + bias ----------------
// MODE_A: 0 plain; 1 A = x + agg (A2); 2 A = relu(A*scale[k]+shift[k]) (BN+ReLU)
// RELU_EPI: relu after bias.
// 64x64 tile, BK=16, 16x16 threads, 4x4 per thread.
template <int MODE_A, int RELU_EPI>
__global__ void gemm_kernel(const float* __restrict__ A,
                            const float* __restrict__ A2,
                            const float* __restrict__ scale,
                            const float* __restrict__ shift,
                            const float* __restrict__ B,
                            const float* __restrict__ bias,
                            float* __restrict__ C,
                            int M, int N, int K) {
    const int BM = 64, BN = 64, BK = 16;
    __shared__ float As[BK][BM];
    __shared__ float Bs[BK][BN];
    int tx = threadIdx.x, ty = threadIdx.y;
    int tid = ty * 16 + tx;
    int m0 = blockIdx.y * BM;
    int n0 = blockIdx.x * BN;
    float acc[4][4] = {};

    for (int kk = 0; kk < K; kk += BK) {
        // A tile -> As[k][m] (transposed for m-contiguous reads)
#pragma unroll
        for (int i = 0; i < 4; ++i) {
            int idx = tid + i * 256;
            int m = idx / BK, k = idx % BK;
            int gm = m0 + m, gk = kk + k;
            float v = 0.f;
            if (gm < M) {
                v = A[(long)gm * K + gk];
                if (MODE_A == 1) v += A2[(long)gm * K + gk];
                if (MODE_A == 2) v = fmaxf(v * scale[gk] + shift[gk], 0.f);
            }
            As[k][m] = v;
        }
        // B tile -> Bs[k][n]
#pragma unroll
        for (int i = 0; i < 4; ++i) {
            int idx = tid + i * 256;
            int k = idx / BN, n = idx % BN;
            int gn = n0 + n;
            float v = 0.f;
            if (gn < N) v = B[(long)(kk + k) * N + gn];
            Bs[k][n] = v;
        }
        __syncthreads();
#pragma unroll
        for (int k = 0; k < BK; ++k) {
            float a[4], b[4];
#pragma unroll
            for (int i = 0; i < 4; ++i) a[i] = As[k][ty * 4 + i];
#pragma unroll
            for (int j = 0; j < 4; ++j) b[j] = Bs[k][tx * 4 + j];
#pragma unroll
            for (int i = 0; i < 4; ++i)
#pragma unroll
                for (int j = 0; j < 4; ++j) acc[i][j] += a[i] * b[j];
        }
        __syncthreads();
    }

#pragma unroll
    for (int i = 0; i < 4; ++i) {
        int gm = m0 + ty * 4 + i;
        if (gm >= M) continue;
#pragma unroll
        for (int j = 0; j < 4; ++j) {
            int gn = n0 + tx * 4 + j;
            if (gn >= N) continue;
            float v = acc[i][j] + bias[gn];
            if (RELU_EPI) v = fmaxf(v, 0.f);
            C[(long)gm * N + gn] = v;
        }
    }
}

extern "C" void kernel_launch(void* const* d_in, const int* in_sizes, int n_in,
                              void* d_out, int out_size, void* d_ws, size_t ws_size,
                              hipStream_t stream) {
    const float* x     = (const float*)d_in[0];
    const int*   ei    = (const int*)d_in[1];
    const float* W1    = (const float*)d_in[2];
    const float* b1    = (const float*)d_in[3];
    const float* gamma = (const float*)d_in[4];
    const float* beta  = (const float*)d_in[5];
    const float* W2    = (const float*)d_in[6];
    const float* b2    = (const float*)d_in[7];
    const float* Wlin  = (const float*)d_in[8];
    const float* blin  = (const float*)d_in[9];
    float* out = (float*)d_out;

    int M  = in_sizes[0] / F_IN;   // 50000
    int nE = in_sizes[1] / 2;      // 600000
    const int* srcIdx = ei;
    const int* dstIdx = ei + nE;

    // workspace layout
    float* agg   = (float*)d_ws;                   // M*128
    float* h1    = agg + (size_t)M * F_IN;         // M*256
    float* h2    = h1 + (size_t)M * DIM_H;         // M*256
    float* stats = h2 + (size_t)M * DIM_H;         // 512 (sum, sumsq)
    float* scale = stats + 2 * DIM_H;              // 256
    float* shift = scale + DIM_H;                  // 256

    hipMemsetAsync(agg, 0, (size_t)M * F_IN * sizeof(float), stream);
    hipMemsetAsync(stats, 0, 2 * DIM_H * sizeof(float), stream);

    // scatter
    {
        int threads = 256;
        long total = (long)nE * 32;
        int blocks = (int)((total + threads - 1) / threads);
        scatter_kernel<<<blocks, threads, 0, stream>>>(x, srcIdx, dstIdx, agg, nE, M);
    }

    dim3 blk(16, 16);
    // GEMM1: h1 = (x + agg) @ W1 + b1
    {
        dim3 grid((DIM_H + 63) / 64, (M + 63) / 64);
        gemm_kernel<1, 0><<<grid, blk, 0, stream>>>(x, agg, nullptr, nullptr,
                                                    W1, b1, h1, M, DIM_H, F_IN);
    }
    // BN stats + finalize
    bn_stats_kernel<<<256, 256, 0, stream>>>(h1, stats, M);
    bn_finalize_kernel<<<1, DIM_H, 0, stream>>>(stats, gamma, beta, scale, shift, M);
    // GEMM2: h2 = relu( relu(bn(h1)) @ W2 + b2 )
    {
        dim3 grid((DIM_H + 63) / 64, (M + 63) / 64);
        gemm_kernel<2, 1><<<grid, blk, 0, stream>>>(h1, nullptr, scale, shift,
                                                    W2, b2, h2, M, DIM_H, DIM_H);
    }
    // GEMM3: out = h2 @ Wlin + blin
    {
        dim3 grid((N_CLASSES + 63) / 64, (M + 63) / 64);
        gemm_kernel<0, 0><<<grid, blk, 0, stream>>>(h2, nullptr, nullptr, nullptr,
                                                    Wlin, blin, out, M, N_CLASSES, DIM_H);
    }
}

// Round 2
// 615.986 us; speedup vs baseline: 2.3171x; 2.3171x over previous
//
#include <hip/hip_runtime.h>

#define F_IN 128
#define DIM_H 256
#define N_CLASSES 40
#define BN_EPS 1e-5f

// ---------------- Phase A: histogram of dst ----------------
__global__ void hist_kernel(const int* __restrict__ dst, int* __restrict__ hist, int nE) {
    int e = blockIdx.x * blockDim.x + threadIdx.x;
    if (e >= nE) return;
    atomicAdd(&hist[dst[e]], 1);
}

// ---------------- Phase B: exclusive scan over M bins (single block) ----------------
__global__ void scan_kernel(const int* __restrict__ hist, int* __restrict__ start, int M) {
    __shared__ int sums[1024];
    int t = threadIdx.x;
    int chunk = (M + 1023) / 1024;
    int i0 = t * chunk, i1 = min(M, i0 + chunk);
    int s = 0;
    for (int i = i0; i < i1; ++i) s += hist[i];
    sums[t] = s;
    __syncthreads();
    for (int off = 1; off < 1024; off <<= 1) {
        int v = 0;
        if (t >= off) v = sums[t - off];
        __syncthreads();
        if (t >= off) sums[t] += v;
        __syncthreads();
    }
    int run = (t == 0) ? 0 : sums[t - 1];
    for (int i = i0; i < i1; ++i) { start[i] = run; run += hist[i]; }
    if (t == 1023) start[M] = run;  // == nE
}

// ---------------- Phase C: bucket-fill src indices ----------------
__global__ void fill_kernel(const int* __restrict__ src, const int* __restrict__ dst,
                            const int* __restrict__ start, int* __restrict__ cursor,
                            int* __restrict__ order, int nE) {
    int e = blockIdx.x * blockDim.x + threadIdx.x;
    if (e >= nE) return;
    int d = dst[e];
    int pos = start[d] + atomicAdd(&cursor[d], 1);
    order[pos] = src[e];
}

// ---------------- Phase D: gather-reduce, one wave per node ----------------
__global__ void gather_agg_kernel(const float* __restrict__ x,
                                  const int* __restrict__ order,
                                  const int* __restrict__ start,
                                  float* __restrict__ agg, int M) {
    int node = blockIdx.x * 4 + (threadIdx.x >> 6);
    if (node >= M) return;
    int lane = threadIdx.x & 63;
    int e0 = start[node], e1 = start[node + 1];
    const float2* xv = (const float2*)x;
    float2 acc = make_float2(0.f, 0.f);
    for (int e = e0; e < e1; ++e) {
        int s = order[e];
        float2 v = xv[(size_t)s * 64 + lane];
        acc.x += v.x;
        acc.y += v.y;
    }
    ((float2*)agg)[(size_t)node * 64 + lane] = acc;
}

// ---------------- BN statistics ----------------
__global__ void bn_stats_kernel(const float* __restrict__ h1,
                                float* __restrict__ stats, int M) {
    int c = threadIdx.x;  // 0..255
    int rows_per_block = (M + gridDim.x - 1) / gridDim.x;
    int r0 = blockIdx.x * rows_per_block;
    int r1 = min(M, r0 + rows_per_block);
    float s = 0.f, ss = 0.f;
    for (int r = r0; r < r1; ++r) {
        float v = h1[(long)r * DIM_H + c];
        s += v;
        ss += v * v;
    }
    atomicAdd(&stats[c], s);
    atomicAdd(&stats[DIM_H + c], ss);
}

__global__ void bn_finalize_kernel(const float* __restrict__ stats,
                                   const float* __restrict__ gamma,
                                   const float* __restrict__ beta,
                                   float* __restrict__ scale,
                                   float* __restrict__ shift, int M) {
    int c = threadIdx.x;
    float inv_m = 1.0f / (float)M;
    float mean = stats[c] * inv_m;
    float var = stats[DIM_H + c] * inv_m - mean * mean;
    float sc = gamma[c] * rsqrtf(var + BN_EPS);
    scale[c] = sc;
    shift[c] = beta[c] - mean * sc;
}

// ---------------- GEMM: C[M,N] = op(A[M,K]) @ B[K,N] + bias ----------------
template <int MODE_A, int RELU_EPI>
__global__ void gemm_kernel(const float* __restrict__ A,
                            const float* __restrict__ A2,
                            const float* __restrict__ scale,
                            const float* __restrict__ shift,
                            const float* __restrict__ B,
                            const float* __restrict__ bias,
                            float* __restrict__ C,
                            int M, int N, int K) {
    const int BM = 64, BN = 64, BK = 16;
    __shared__ float As[BK][BM];
    __shared__ float Bs[BK][BN];
    int tx = threadIdx.x, ty = threadIdx.y;
    int tid = ty * 16 + tx;
    int m0 = blockIdx.y * BM;
    int n0 = blockIdx.x * BN;
    float acc[4][4] = {};

    for (int kk = 0; kk < K; kk += BK) {
#pragma unroll
        for (int i = 0; i < 4; ++i) {
            int idx = tid + i * 256;
            int m = idx / BK, k = idx % BK;
            int gm = m0 + m, gk = kk + k;
            float v = 0.f;
            if (gm < M) {
                v = A[(long)gm * K + gk];
                if (MODE_A == 1) v += A2[(long)gm * K + gk];
                if (MODE_A == 2) v = fmaxf(v * scale[gk] + shift[gk], 0.f);
            }
            As[k][m] = v;
        }
#pragma unroll
        for (int i = 0; i < 4; ++i) {
            int idx = tid + i * 256;
            int k = idx / BN, n = idx % BN;
            int gn = n0 + n;
            float v = 0.f;
            if (gn < N) v = B[(long)(kk + k) * N + gn];
            Bs[k][n] = v;
        }
        __syncthreads();
#pragma unroll
        for (int k = 0; k < BK; ++k) {
            float a[4], b[4];
#pragma unroll
            for (int i = 0; i < 4; ++i) a[i] = As[k][ty * 4 + i];
#pragma unroll
            for (int j = 0; j < 4; ++j) b[j] = Bs[k][tx * 4 + j];
#pragma unroll
            for (int i = 0; i < 4; ++i)
#pragma unroll
                for (int j = 0; j < 4; ++j) acc[i][j] += a[i] * b[j];
        }
        __syncthreads();
    }

#pragma unroll
    for (int i = 0; i < 4; ++i) {
        int gm = m0 + ty * 4 + i;
        if (gm >= M) continue;
#pragma unroll
        for (int j = 0; j < 4; ++j) {
            int gn = n0 + tx * 4 + j;
            if (gn >= N) continue;
            float v = acc[i][j] + bias[gn];
            if (RELU_EPI) v = fmaxf(v, 0.f);
            C[(long)gm * N + gn] = v;
        }
    }
}

extern "C" void kernel_launch(void* const* d_in, const int* in_sizes, int n_in,
                              void* d_out, int out_size, void* d_ws, size_t ws_size,
                              hipStream_t stream) {
    const float* x     = (const float*)d_in[0];
    const int*   ei    = (const int*)d_in[1];
    const float* W1    = (const float*)d_in[2];
    const float* b1    = (const float*)d_in[3];
    const float* gamma = (const float*)d_in[4];
    const float* beta  = (const float*)d_in[5];
    const float* W2    = (const float*)d_in[6];
    const float* b2    = (const float*)d_in[7];
    const float* Wlin  = (const float*)d_in[8];
    const float* blin  = (const float*)d_in[9];
    float* out = (float*)d_out;

    int M  = in_sizes[0] / F_IN;   // 50000
    int nE = in_sizes[1] / 2;      // 600000
    const int* srcIdx = ei;
    const int* dstIdx = ei + nE;

    // workspace layout (floats)
    float* agg   = (float*)d_ws;                   // M*128
    float* h1    = agg + (size_t)M * F_IN;         // M*256
    float* h2    = h1 + (size_t)M * DIM_H;         // M*256
    float* stats = h2 + (size_t)M * DIM_H;         // 512 (sum, sumsq)
    float* scale = stats + 2 * DIM_H;              // 256
    float* shift = scale + DIM_H;                  // 256
    // int scratch aliased over h2 (dead until GEMM2)
    int* hist   = (int*)h2;                        // M
    int* start  = hist + M;                        // M+1
    int* cursor = start + (M + 1);                 // M
    int* order  = cursor + M;                      // nE

    hipMemsetAsync(hist, 0, (size_t)M * sizeof(int), stream);
    hipMemsetAsync(cursor, 0, (size_t)M * sizeof(int), stream);
    hipMemsetAsync(stats, 0, 2 * DIM_H * sizeof(float), stream);

    int tB = 256;
    hist_kernel<<<(nE + tB - 1) / tB, tB, 0, stream>>>(dstIdx, hist, nE);
    scan_kernel<<<1, 1024, 0, stream>>>(hist, start, M);
    fill_kernel<<<(nE + tB - 1) / tB, tB, 0, stream>>>(srcIdx, dstIdx, start, cursor, order, nE);
    gather_agg_kernel<<<(M + 3) / 4, 256, 0, stream>>>(x, order, start, agg, M);

    dim3 blk(16, 16);
    // GEMM1: h1 = (x + agg) @ W1 + b1
    {
        dim3 grid((DIM_H + 63) / 64, (M + 63) / 64);
        gemm_kernel<1, 0><<<grid, blk, 0, stream>>>(x, agg, nullptr, nullptr,
                                                    W1, b1, h1, M, DIM_H, F_IN);
    }
    bn_stats_kernel<<<256, 256, 0, stream>>>(h1, stats, M);
    bn_finalize_kernel<<<1, DIM_H, 0, stream>>>(stats, gamma, beta, scale, shift, M);
    // GEMM2: h2 = relu( relu(bn(h1)) @ W2 + b2 )  (overwrites int scratch — dead by now)
    {
        dim3 grid((DIM_H + 63) / 64, (M + 63) / 64);
        gemm_kernel<2, 1><<<grid, blk, 0, stream>>>(h1, nullptr, scale, shift,
                                                    W2, b2, h2, M, DIM_H, DIM_H);
    }
    // GEMM3: out = h2 @ Wlin + blin
    {
        dim3 grid((N_CLASSES + 63) / 64, (M + 63) / 64);
        gemm_kernel<0, 0><<<grid, blk, 0, stream>>>(h2, nullptr, nullptr, nullptr,
                                                    Wlin, blin, out, M, N_CLASSES, DIM_H);
    }
}

// Round 3
// 407.317 us; speedup vs baseline: 3.5042x; 1.5123x over previous
//
#include <hip/hip_runtime.h>

#define F_IN 128
#define DIM_H 256
#define N_CLASSES 40
#define BN_EPS 1e-5f
#define M_PAD 50176  // ceil(50000/256)*256 — max padded rows any GEMM reads

typedef short bf16x8 __attribute__((ext_vector_type(8)));
typedef float f32x4 __attribute__((ext_vector_type(4)));

__device__ __forceinline__ unsigned short f2bf(float f) {
    union { float f; unsigned u; } v; v.f = f;
    unsigned r = v.u + 0x7fff + ((v.u >> 16) & 1);  // RNE
    return (unsigned short)(r >> 16);
}

// ---------------- Phase A: histogram of dst ----------------
__global__ void hist_kernel(const int* __restrict__ dst, int* __restrict__ hist, int nE) {
    int e = blockIdx.x * blockDim.x + threadIdx.x;
    if (e >= nE) return;
    atomicAdd(&hist[dst[e]], 1);
}

// ---------------- Phase B: exclusive scan over M bins (single block) ----------------
__global__ void scan_kernel(const int* __restrict__ hist, int* __restrict__ start, int M) {
    __shared__ int sums[1024];
    int t = threadIdx.x;
    int chunk = (M + 1023) / 1024;
    int i0 = t * chunk, i1 = min(M, i0 + chunk);
    int s = 0;
    for (int i = i0; i < i1; ++i) s += hist[i];
    sums[t] = s;
    __syncthreads();
    for (int off = 1; off < 1024; off <<= 1) {
        int v = 0;
        if (t >= off) v = sums[t - off];
        __syncthreads();
        if (t >= off) sums[t] += v;
        __syncthreads();
    }
    int run = (t == 0) ? 0 : sums[t - 1];
    for (int i = i0; i < i1; ++i) { start[i] = run; run += hist[i]; }
    if (t == 1023) start[M] = run;  // == nE
}

// ---------------- Phase C: bucket-fill src indices ----------------
__global__ void fill_kernel(const int* __restrict__ src, const int* __restrict__ dst,
                            const int* __restrict__ start, int* __restrict__ cursor,
                            int* __restrict__ order, int nE) {
    int e = blockIdx.x * blockDim.x + threadIdx.x;
    if (e >= nE) return;
    int d = dst[e];
    int pos = start[d] + atomicAdd(&cursor[d], 1);
    order[pos] = src[e];
}

// ---------------- Phase D: gather-reduce -> A1 = bf16(x + agg) ----------------
// half-wave (32 lanes) per node, float4 loads (row = 32 float4)
__global__ void gather_agg_kernel(const float* __restrict__ x,
                                  const int* __restrict__ order,
                                  const int* __restrict__ start,
                                  unsigned short* __restrict__ A1, int M) {
    int node = blockIdx.x * 8 + (threadIdx.x >> 5);
    if (node >= M) return;
    int lane = threadIdx.x & 31;
    const float4* xv = (const float4*)x;
    float4 acc = xv[(size_t)node * 32 + lane];  // the "+x" term
    int e0 = start[node], e1 = start[node + 1];
    for (int e = e0; e < e1; ++e) {
        int s = order[e];
        float4 v = xv[(size_t)s * 32 + lane];
        acc.x += v.x; acc.y += v.y; acc.z += v.z; acc.w += v.w;
    }
    ushort4 o;
    o.x = f2bf(acc.x); o.y = f2bf(acc.y); o.z = f2bf(acc.z); o.w = f2bf(acc.w);
    ((ushort4*)A1)[(size_t)node * 32 + lane] = o;
}

// ---------------- weight transpose + bf16: Wt[n][k] = bf16(W[k][n]) ----------------
__global__ void wtrans_kernel(const float* __restrict__ W, unsigned short* __restrict__ Wt,
                              int K, int N, int Npad) {
    int idx = blockIdx.x * 256 + threadIdx.x;
    if (idx >= Npad * K) return;
    int n = idx / K, k = idx - n * K;
    float v = (n < N) ? W[(long)k * N + n] : 0.f;
    Wt[idx] = f2bf(v);
}

// ---------------- BN finalize ----------------
__global__ void bn_finalize_kernel(const float* __restrict__ stats,
                                   const float* __restrict__ gamma,
                                   const float* __restrict__ beta,
                                   float* __restrict__ scale,
                                   float* __restrict__ shift, int M) {
    int c = threadIdx.x;
    float inv_m = 1.0f / (float)M;
    float mean = stats[c] * inv_m;
    float var = stats[DIM_H + c] * inv_m - mean * mean;
    float sc = gamma[c] * rsqrtf(var + BN_EPS);
    scale[c] = sc;
    shift[c] = beta[c] - mean * sc;
}

// ---------------- BN apply + ReLU + bf16 cast ----------------
__global__ void bn_apply_kernel(const float* __restrict__ h1,
                                const float* __restrict__ scale,
                                const float* __restrict__ shift,
                                unsigned short* __restrict__ hb, int M) {
    long i = (long)blockIdx.x * 256 + threadIdx.x;  // over M*64 float4 groups
    if (i >= (long)M * 64) return;
    int c4 = (int)(i & 63) * 4;
    float4 v = ((const float4*)h1)[i];
    float4 sc = *(const float4*)(scale + c4);
    float4 sh = *(const float4*)(shift + c4);
    ushort4 o;
    o.x = f2bf(fmaxf(v.x * sc.x + sh.x, 0.f));
    o.y = f2bf(fmaxf(v.y * sc.y + sh.y, 0.f));
    o.z = f2bf(fmaxf(v.z * sc.z + sh.z, 0.f));
    o.w = f2bf(fmaxf(v.w * sc.w + sh.w, 0.f));
    ((ushort4*)hb)[i] = o;
}

// ---------------- MFMA GEMM: C[M,Nout] = A[M,K](bf16) @ Bt[n][k](bf16) + bias ----------------
// Block: WM x WN waves, each wave computes 64x64 (4x4 tiles of 16x16x32 MFMA).
// MODE 0: fp32 out + fused BN column sums (atomicAdd into stats)
// MODE 1: relu -> bf16 out
// MODE 2: fp32 out with col < Nout guard (Nout=40)
template <int WM, int WN, int K, int MODE>
__global__ __launch_bounds__(WM* WN * 64) void mfma_gemm(
    const unsigned short* __restrict__ A,  // [M_PAD, K] bf16
    const unsigned short* __restrict__ Bt, // [Npad, K] bf16 (N-major, K-contig)
    const float* __restrict__ bias,
    void* __restrict__ Cout,
    float* __restrict__ stats,
    int M, int Nout) {
    const int BM = WM * 64, BN = WN * 64;
    int wave = threadIdx.x >> 6;
    int lane = threadIdx.x & 63;
    int wm = wave / WN, wn = wave % WN;
    int l15 = lane & 15, q = lane >> 4;
    long row0 = (long)blockIdx.y * BM + wm * 64;
    long col0 = (long)blockIdx.x * BN + wn * 64;

    f32x4 acc[4][4] = {};
    const unsigned short* Ap = A + (row0 + l15) * K + q * 8;
    const unsigned short* Bp = Bt + (col0 + l15) * K + q * 8;

#pragma unroll
    for (int kk = 0; kk < K; kk += 32) {
        bf16x8 af[4], bfr[4];
#pragma unroll
        for (int mt = 0; mt < 4; ++mt)
            af[mt] = *(const bf16x8*)(Ap + (long)mt * 16 * K + kk);
#pragma unroll
        for (int nt = 0; nt < 4; ++nt)
            bfr[nt] = *(const bf16x8*)(Bp + (long)nt * 16 * K + kk);
#pragma unroll
        for (int mt = 0; mt < 4; ++mt)
#pragma unroll
            for (int nt = 0; nt < 4; ++nt)
                acc[mt][nt] = __builtin_amdgcn_mfma_f32_16x16x32_bf16(
                    af[mt], bfr[nt], acc[mt][nt], 0, 0, 0);
    }

#pragma unroll
    for (int nt = 0; nt < 4; ++nt) {
        long col = col0 + nt * 16 + l15;
        float b = (MODE == 2) ? ((col < Nout) ? bias[col] : 0.f) : bias[col];
        float s = 0.f, ss = 0.f;
#pragma unroll
        for (int mt = 0; mt < 4; ++mt) {
#pragma unroll
            for (int r = 0; r < 4; ++r) {
                long row = row0 + mt * 16 + q * 4 + r;
                float v = acc[mt][nt][r] + b;
                if (MODE == 1) v = fmaxf(v, 0.f);
                if (row < M) {
                    if (MODE == 0) {
                        ((float*)Cout)[row * DIM_H + col] = v;
                        s += v; ss += v * v;
                    } else if (MODE == 1) {
                        ((unsigned short*)Cout)[row * DIM_H + col] = f2bf(v);
                    } else {
                        if (col < Nout) ((float*)Cout)[row * Nout + col] = v;
                    }
                }
            }
        }
        if (MODE == 0) {
            s += __shfl_xor(s, 16, 64);  s += __shfl_xor(s, 32, 64);
            ss += __shfl_xor(ss, 16, 64); ss += __shfl_xor(ss, 32, 64);
            if (lane < 16) {
                atomicAdd(&stats[col], s);
                atomicAdd(&stats[DIM_H + col], ss);
            }
        }
    }
}

extern "C" void kernel_launch(void* const* d_in, const int* in_sizes, int n_in,
                              void* d_out, int out_size, void* d_ws, size_t ws_size,
                              hipStream_t stream) {
    const float* x     = (const float*)d_in[0];
    const int*   ei    = (const int*)d_in[1];
    const float* W1    = (const float*)d_in[2];
    const float* b1    = (const float*)d_in[3];
    const float* gamma = (const float*)d_in[4];
    const float* beta  = (const float*)d_in[5];
    const float* W2    = (const float*)d_in[6];
    const float* b2    = (const float*)d_in[7];
    const float* Wlin  = (const float*)d_in[8];
    const float* blin  = (const float*)d_in[9];
    float* out = (float*)d_out;

    int M  = in_sizes[0] / F_IN;  // 50000
    int nE = in_sizes[1] / 2;     // 600000
    const int* srcIdx = ei;
    const int* dstIdx = ei + nE;

    // ---- workspace layout (total ~119 MB) ----
    unsigned short* A1bf  = (unsigned short*)d_ws;           // M_PAD*128 bf16
    float*          h1    = (float*)(A1bf + (size_t)M_PAD * F_IN);   // M_PAD*256 f32
    unsigned short* h1nbf = (unsigned short*)(h1 + (size_t)M_PAD * DIM_H); // M_PAD*256 bf16
    unsigned short* h2bf  = h1nbf + (size_t)M_PAD * DIM_H;   // M_PAD*256 bf16
    unsigned short* W1t   = h2bf + (size_t)M_PAD * DIM_H;    // 256*128
    unsigned short* W2t   = W1t + DIM_H * F_IN;              // 256*256
    unsigned short* Wlt   = W2t + DIM_H * DIM_H;             // 64*256 (zero-padded)
    float*          stats = (float*)(Wlt + 64 * DIM_H);      // 512
    float*          scale = stats + 2 * DIM_H;               // 256
    float*          shift = scale + DIM_H;                   // 256
    int*            hist  = (int*)(shift + DIM_H);           // M
    int*            start = hist + M;                        // M+1
    int*            cursor= start + (M + 1);                 // M
    int*            order = cursor + M;                      // nE

    hipMemsetAsync(hist, 0, (size_t)M * sizeof(int), stream);
    hipMemsetAsync(cursor, 0, (size_t)M * sizeof(int), stream);
    hipMemsetAsync(stats, 0, 2 * DIM_H * sizeof(float), stream);

    int tB = 256;
    hist_kernel<<<(nE + tB - 1) / tB, tB, 0, stream>>>(dstIdx, hist, nE);
    scan_kernel<<<1, 1024, 0, stream>>>(hist, start, M);
    fill_kernel<<<(nE + tB - 1) / tB, tB, 0, stream>>>(srcIdx, dstIdx, start, cursor, order, nE);
    gather_agg_kernel<<<(M + 7) / 8, 256, 0, stream>>>(x, order, start, A1bf, M);

    // weight transposes (bf16, N-major)
    wtrans_kernel<<<(DIM_H * F_IN + 255) / 256, 256, 0, stream>>>(W1, W1t, F_IN, DIM_H, DIM_H);
    wtrans_kernel<<<(DIM_H * DIM_H + 255) / 256, 256, 0, stream>>>(W2, W2t, DIM_H, DIM_H, DIM_H);
    wtrans_kernel<<<(64 * DIM_H + 255) / 256, 256, 0, stream>>>(Wlin, Wlt, DIM_H, N_CLASSES, 64);

    // GEMM1: h1 = A1 @ W1 + b1  (fp32 out, fused BN column sums)
    mfma_gemm<2, 2, F_IN, 0><<<dim3(2, (M + 127) / 128), 256, 0, stream>>>(
        A1bf, W1t, b1, h1, stats, M, DIM_H);
    bn_finalize_kernel<<<1, DIM_H, 0, stream>>>(stats, gamma, beta, scale, shift, M);
    bn_apply_kernel<<<(int)(((long)M * 64 + 255) / 256), 256, 0, stream>>>(h1, scale, shift, h1nbf, M);
    // GEMM2: h2 = relu(h1n @ W2 + b2) -> bf16
    mfma_gemm<2, 2, DIM_H, 1><<<dim3(2, (M + 127) / 128), 256, 0, stream>>>(
        h1nbf, W2t, b2, h2bf, nullptr, M, DIM_H);
    // GEMM3: out = h2 @ Wlin + blin  (fp32, col<40)
    mfma_gemm<4, 1, DIM_H, 2><<<dim3(1, (M + 255) / 256), 256, 0, stream>>>(
        h2bf, Wlt, blin, out, nullptr, M, N_CLASSES);
}

// Round 4
// 340.985 us; speedup vs baseline: 4.1859x; 1.1945x over previous
//
#include <hip/hip_runtime.h>

#define F_IN 128
#define DIM_H 256
#define N_CLASSES 40
#define BN_EPS 1e-5f
#define M_PAD 50176  // ceil(50000/256)*256 — max padded rows any GEMM reads

typedef short bf16x8 __attribute__((ext_vector_type(8)));
typedef float f32x4 __attribute__((ext_vector_type(4)));

__device__ __forceinline__ unsigned short f2bf(float f) {
    union { float f; unsigned u; } v; v.f = f;
    unsigned r = v.u + 0x7fff + ((v.u >> 16) & 1);  // RNE
    return (unsigned short)(r >> 16);
}

// ---------------- Phase A: histogram of dst ----------------
__global__ void hist_kernel(const int* __restrict__ dst, int* __restrict__ hist, int nE) {
    int e = blockIdx.x * blockDim.x + threadIdx.x;
    if (e >= nE) return;
    atomicAdd(&hist[dst[e]], 1);
}

// ---------------- Phase B: hierarchical exclusive scan (3 wide kernels) ----------------
__global__ void scan_blocks_kernel(const int* __restrict__ hist,
                                   int* __restrict__ blockSums, int M) {
    __shared__ int lds[256];
    int t = threadIdx.x;
    int i = blockIdx.x * 256 + t;
    lds[t] = (i < M) ? hist[i] : 0;
    __syncthreads();
    for (int off = 128; off > 0; off >>= 1) {
        if (t < off) lds[t] += lds[t + off];
        __syncthreads();
    }
    if (t == 0) blockSums[blockIdx.x] = lds[0];
}

__global__ void scan_offsets_kernel(const int* __restrict__ blockSums,
                                    int* __restrict__ blockOffs,
                                    int nB, int* __restrict__ start, int M, int nE) {
    __shared__ int lds[256];
    int t = threadIdx.x;
    int orig = (t < nB) ? blockSums[t] : 0;
    lds[t] = orig;
    __syncthreads();
    for (int off = 1; off < 256; off <<= 1) {
        int v = (t >= off) ? lds[t - off] : 0;
        __syncthreads();
        lds[t] += v;
        __syncthreads();
    }
    if (t < nB) blockOffs[t] = lds[t] - orig;  // exclusive prefix of block sums
    if (t == 0) start[M] = nE;
}

__global__ void scan_final_kernel(const int* __restrict__ hist,
                                  const int* __restrict__ blockOffs,
                                  int* __restrict__ start, int M) {
    __shared__ int lds[256];
    int t = threadIdx.x;
    int i = blockIdx.x * 256 + t;
    int orig = (i < M) ? hist[i] : 0;
    lds[t] = orig;
    __syncthreads();
    for (int off = 1; off < 256; off <<= 1) {
        int v = (t >= off) ? lds[t - off] : 0;
        __syncthreads();
        lds[t] += v;
        __syncthreads();
    }
    if (i < M) start[i] = blockOffs[blockIdx.x] + lds[t] - orig;
}

// ---------------- Phase C: bucket-fill src indices ----------------
__global__ void fill_kernel(const int* __restrict__ src, const int* __restrict__ dst,
                            const int* __restrict__ start, int* __restrict__ cursor,
                            int* __restrict__ order, int nE) {
    int e = blockIdx.x * blockDim.x + threadIdx.x;
    if (e >= nE) return;
    int d = dst[e];
    int pos = start[d] + atomicAdd(&cursor[d], 1);
    order[pos] = src[e];
}

// ---------------- Phase D: gather-reduce -> A1 = bf16(x + agg) ----------------
// half-wave (32 lanes) per node, float4 loads (row = 32 float4)
__global__ void gather_agg_kernel(const float* __restrict__ x,
                                  const int* __restrict__ order,
                                  const int* __restrict__ start,
                                  unsigned short* __restrict__ A1, int M) {
    int node = blockIdx.x * 8 + (threadIdx.x >> 5);
    if (node >= M) return;
    int lane = threadIdx.x & 31;
    const float4* xv = (const float4*)x;
    float4 acc = xv[(size_t)node * 32 + lane];  // the "+x" term
    int e0 = start[node], e1 = start[node + 1];
    for (int e = e0; e < e1; ++e) {
        int s = order[e];
        float4 v = xv[(size_t)s * 32 + lane];
        acc.x += v.x; acc.y += v.y; acc.z += v.z; acc.w += v.w;
    }
    ushort4 o;
    o.x = f2bf(acc.x); o.y = f2bf(acc.y); o.z = f2bf(acc.z); o.w = f2bf(acc.w);
    ((ushort4*)A1)[(size_t)node * 32 + lane] = o;
}

// ---------------- weight transpose + bf16: Wt[n][k] = bf16(W[k][n]) ----------------
__global__ void wtrans_kernel(const float* __restrict__ W, unsigned short* __restrict__ Wt,
                              int K, int N, int Npad) {
    int idx = blockIdx.x * 256 + threadIdx.x;
    if (idx >= Npad * K) return;
    int n = idx / K, k = idx - n * K;
    float v = (n < N) ? W[(long)k * N + n] : 0.f;
    Wt[idx] = f2bf(v);
}

// ---------------- BN finalize ----------------
__global__ void bn_finalize_kernel(const float* __restrict__ stats,
                                   const float* __restrict__ gamma,
                                   const float* __restrict__ beta,
                                   float* __restrict__ scale,
                                   float* __restrict__ shift, int M) {
    int c = threadIdx.x;
    float inv_m = 1.0f / (float)M;
    float mean = stats[c] * inv_m;
    float var = stats[DIM_H + c] * inv_m - mean * mean;
    float sc = gamma[c] * rsqrtf(var + BN_EPS);
    scale[c] = sc;
    shift[c] = beta[c] - mean * sc;
}

// ---------------- BN apply + ReLU + bf16 cast ----------------
__global__ void bn_apply_kernel(const float* __restrict__ h1,
                                const float* __restrict__ scale,
                                const float* __restrict__ shift,
                                unsigned short* __restrict__ hb, int M) {
    long i = (long)blockIdx.x * 256 + threadIdx.x;  // over M*64 float4 groups
    if (i >= (long)M * 64) return;
    int c4 = (int)(i & 63) * 4;
    float4 v = ((const float4*)h1)[i];
    float4 sc = *(const float4*)(scale + c4);
    float4 sh = *(const float4*)(shift + c4);
    ushort4 o;
    o.x = f2bf(fmaxf(v.x * sc.x + sh.x, 0.f));
    o.y = f2bf(fmaxf(v.y * sc.y + sh.y, 0.f));
    o.z = f2bf(fmaxf(v.z * sc.z + sh.z, 0.f));
    o.w = f2bf(fmaxf(v.w * sc.w + sh.w, 0.f));
    ((ushort4*)hb)[i] = o;
}

// ---------------- MFMA GEMM: C[M,Nout] = A[M,K](bf16) @ Bt[n][k](bf16) + bias ----------------
// Block: WM x WN waves, each wave computes 64x64 (4x4 tiles of 16x16x32 MFMA).
// MODE 0: fp32 out + fused BN column sums (atomicAdd into stats)
// MODE 1: relu -> bf16 out
// MODE 2: fp32 out with col < Nout guard (Nout=40)
template <int WM, int WN, int K, int MODE>
__global__ __launch_bounds__(WM* WN * 64) void mfma_gemm(
    const unsigned short* __restrict__ A,  // [M_PAD, K] bf16
    const unsigned short* __restrict__ Bt, // [Npad, K] bf16 (N-major, K-contig)
    const float* __restrict__ bias,
    void* __restrict__ Cout,
    float* __restrict__ stats,
    int M, int Nout) {
    const int BM = WM * 64, BN = WN * 64;
    int wave = threadIdx.x >> 6;
    int lane = threadIdx.x & 63;
    int wm = wave / WN, wn = wave % WN;
    int l15 = lane & 15, q = lane >> 4;
    long row0 = (long)blockIdx.y * BM + wm * 64;
    long col0 = (long)blockIdx.x * BN + wn * 64;

    f32x4 acc[4][4] = {};
    const unsigned short* Ap = A + (row0 + l15) * K + q * 8;
    const unsigned short* Bp = Bt + (col0 + l15) * K + q * 8;

#pragma unroll
    for (int kk = 0; kk < K; kk += 32) {
        bf16x8 af[4], bfr[4];
#pragma unroll
        for (int mt = 0; mt < 4; ++mt)
            af[mt] = *(const bf16x8*)(Ap + (long)mt * 16 * K + kk);
#pragma unroll
        for (int nt = 0; nt < 4; ++nt)
            bfr[nt] = *(const bf16x8*)(Bp + (long)nt * 16 * K + kk);
#pragma unroll
        for (int mt = 0; mt < 4; ++mt)
#pragma unroll
            for (int nt = 0; nt < 4; ++nt)
                acc[mt][nt] = __builtin_amdgcn_mfma_f32_16x16x32_bf16(
                    af[mt], bfr[nt], acc[mt][nt], 0, 0, 0);
    }

#pragma unroll
    for (int nt = 0; nt < 4; ++nt) {
        long col = col0 + nt * 16 + l15;
        float b = (MODE == 2) ? ((col < Nout) ? bias[col] : 0.f) : bias[col];
        float s = 0.f, ss = 0.f;
#pragma unroll
        for (int mt = 0; mt < 4; ++mt) {
#pragma unroll
            for (int r = 0; r < 4; ++r) {
                long row = row0 + mt * 16 + q * 4 + r;
                float v = acc[mt][nt][r] + b;
                if (MODE == 1) v = fmaxf(v, 0.f);
                if (row < M) {
                    if (MODE == 0) {
                        ((float*)Cout)[row * DIM_H + col] = v;
                        s += v; ss += v * v;
                    } else if (MODE == 1) {
                        ((unsigned short*)Cout)[row * DIM_H + col] = f2bf(v);
                    } else {
                        if (col < Nout) ((float*)Cout)[row * Nout + col] = v;
                    }
                }
            }
        }
        if (MODE == 0) {
            s += __shfl_xor(s, 16, 64);  s += __shfl_xor(s, 32, 64);
            ss += __shfl_xor(ss, 16, 64); ss += __shfl_xor(ss, 32, 64);
            if (lane < 16) {
                atomicAdd(&stats[col], s);
                atomicAdd(&stats[DIM_H + col], ss);
            }
        }
    }
}

extern "C" void kernel_launch(void* const* d_in, const int* in_sizes, int n_in,
                              void* d_out, int out_size, void* d_ws, size_t ws_size,
                              hipStream_t stream) {
    const float* x     = (const float*)d_in[0];
    const int*   ei    = (const int*)d_in[1];
    const float* W1    = (const float*)d_in[2];
    const float* b1    = (const float*)d_in[3];
    const float* gamma = (const float*)d_in[4];
    const float* beta  = (const float*)d_in[5];
    const float* W2    = (const float*)d_in[6];
    const float* b2    = (const float*)d_in[7];
    const float* Wlin  = (const float*)d_in[8];
    const float* blin  = (const float*)d_in[9];
    float* out = (float*)d_out;

    int M  = in_sizes[0] / F_IN;  // 50000
    int nE = in_sizes[1] / 2;     // 600000
    const int* srcIdx = ei;
    const int* dstIdx = ei + nE;
    int nB = (M + 255) / 256;     // 196 scan blocks

    // ---- workspace layout ----
    unsigned short* A1bf  = (unsigned short*)d_ws;           // M_PAD*128 bf16
    float*          h1    = (float*)(A1bf + (size_t)M_PAD * F_IN);   // M_PAD*256 f32
    unsigned short* h1nbf = (unsigned short*)(h1 + (size_t)M_PAD * DIM_H); // M_PAD*256 bf16
    unsigned short* h2bf  = h1nbf + (size_t)M_PAD * DIM_H;   // M_PAD*256 bf16
    unsigned short* W1t   = h2bf + (size_t)M_PAD * DIM_H;    // 256*128
    unsigned short* W2t   = W1t + DIM_H * F_IN;              // 256*256
    unsigned short* Wlt   = W2t + DIM_H * DIM_H;             // 64*256 (zero-padded)
    float*          stats = (float*)(Wlt + 64 * DIM_H);      // 512
    float*          scale = stats + 2 * DIM_H;               // 256
    float*          shift = scale + DIM_H;                   // 256
    int*            hist  = (int*)(shift + DIM_H);           // M
    int*            start = hist + M;                        // M+1
    int*            cursor= start + (M + 1);                 // M
    int*            blockSums = cursor + M;                  // nB
    int*            blockOffs = blockSums + 256;             // nB
    int*            order = blockOffs + 256;                 // nE

    hipMemsetAsync(hist, 0, (size_t)M * sizeof(int), stream);
    hipMemsetAsync(cursor, 0, (size_t)M * sizeof(int), stream);
    hipMemsetAsync(stats, 0, 2 * DIM_H * sizeof(float), stream);

    int tB = 256;
    hist_kernel<<<(nE + tB - 1) / tB, tB, 0, stream>>>(dstIdx, hist, nE);
    scan_blocks_kernel<<<nB, 256, 0, stream>>>(hist, blockSums, M);
    scan_offsets_kernel<<<1, 256, 0, stream>>>(blockSums, blockOffs, nB, start, M, nE);
    scan_final_kernel<<<nB, 256, 0, stream>>>(hist, blockOffs, start, M);
    fill_kernel<<<(nE + tB - 1) / tB, tB, 0, stream>>>(srcIdx, dstIdx, start, cursor, order, nE);
    gather_agg_kernel<<<(M + 7) / 8, 256, 0, stream>>>(x, order, start, A1bf, M);

    // weight transposes (bf16, N-major)
    wtrans_kernel<<<(DIM_H * F_IN + 255) / 256, 256, 0, stream>>>(W1, W1t, F_IN, DIM_H, DIM_H);
    wtrans_kernel<<<(DIM_H * DIM_H + 255) / 256, 256, 0, stream>>>(W2, W2t, DIM_H, DIM_H, DIM_H);
    wtrans_kernel<<<(64 * DIM_H + 255) / 256, 256, 0, stream>>>(Wlin, Wlt, DIM_H, N_CLASSES, 64);

    // GEMM1: h1 = A1 @ W1 + b1  (fp32 out, fused BN column sums)
    mfma_gemm<2, 2, F_IN, 0><<<dim3(2, (M + 127) / 128), 256, 0, stream>>>(
        A1bf, W1t, b1, h1, stats, M, DIM_H);
    bn_finalize_kernel<<<1, DIM_H, 0, stream>>>(stats, gamma, beta, scale, shift, M);
    bn_apply_kernel<<<(int)(((long)M * 64 + 255) / 256), 256, 0, stream>>>(h1, scale, shift, h1nbf, M);
    // GEMM2: h2 = relu(h1n @ W2 + b2) -> bf16
    mfma_gemm<2, 2, DIM_H, 1><<<dim3(2, (M + 127) / 128), 256, 0, stream>>>(
        h1nbf, W2t, b2, h2bf, nullptr, M, DIM_H);
    // GEMM3: out = h2 @ Wlin + blin  (fp32, col<40)
    mfma_gemm<4, 1, DIM_H, 2><<<dim3(1, (M + 255) / 256), 256, 0, stream>>>(
        h2bf, Wlt, blin, out, nullptr, M, N_CLASSES);
}

// Round 5
// 308.343 us; speedup vs baseline: 4.6290x; 1.1059x over previous
//
#include <hip/hip_runtime.h>

#define F_IN 128
#define DIM_H 256
#define N_CLASSES 40
#define BN_EPS 1e-5f
#define M_PAD 50176  // ceil(50000/256)*256 — max padded rows any GEMM reads

typedef short bf16x8 __attribute__((ext_vector_type(8)));
typedef float f32x4 __attribute__((ext_vector_type(4)));

__device__ __forceinline__ unsigned short f2bf(float f) {
    union { float f; unsigned u; } v; v.f = f;
    unsigned r = v.u + 0x7fff + ((v.u >> 16) & 1);  // RNE
    return (unsigned short)(r >> 16);
}
__device__ __forceinline__ float bf2f(unsigned short u) {
    union { unsigned u; float f; } v; v.u = ((unsigned)u) << 16;
    return v.f;
}

// ---------------- Phase A: histogram of dst ----------------
__global__ void hist_kernel(const int* __restrict__ dst, int* __restrict__ hist, int nE) {
    int e = blockIdx.x * blockDim.x + threadIdx.x;
    if (e >= nE) return;
    atomicAdd(&hist[dst[e]], 1);
}

// ---------------- Phase B: hierarchical exclusive scan ----------------
__global__ void scan_blocks_kernel(const int* __restrict__ hist,
                                   int* __restrict__ blockSums, int M) {
    __shared__ int lds[256];
    int t = threadIdx.x;
    int i = blockIdx.x * 256 + t;
    lds[t] = (i < M) ? hist[i] : 0;
    __syncthreads();
    for (int off = 128; off > 0; off >>= 1) {
        if (t < off) lds[t] += lds[t + off];
        __syncthreads();
    }
    if (t == 0) blockSums[blockIdx.x] = lds[0];
}

__global__ void scan_offsets_kernel(const int* __restrict__ blockSums,
                                    int* __restrict__ blockOffs,
                                    int nB, int* __restrict__ start, int M, int nE) {
    __shared__ int lds[256];
    int t = threadIdx.x;
    int orig = (t < nB) ? blockSums[t] : 0;
    lds[t] = orig;
    __syncthreads();
    for (int off = 1; off < 256; off <<= 1) {
        int v = (t >= off) ? lds[t - off] : 0;
        __syncthreads();
        lds[t] += v;
        __syncthreads();
    }
    if (t < nB) blockOffs[t] = lds[t] - orig;
    if (t == 0) start[M] = nE;
}

__global__ void scan_final_kernel(const int* __restrict__ hist,
                                  const int* __restrict__ blockOffs,
                                  int* __restrict__ start, int M) {
    __shared__ int lds[256];
    int t = threadIdx.x;
    int i = blockIdx.x * 256 + t;
    int orig = (i < M) ? hist[i] : 0;
    lds[t] = orig;
    __syncthreads();
    for (int off = 1; off < 256; off <<= 1) {
        int v = (t >= off) ? lds[t - off] : 0;
        __syncthreads();
        lds[t] += v;
        __syncthreads();
    }
    if (i < M) start[i] = blockOffs[blockIdx.x] + lds[t] - orig;
}

// ---------------- Phase C: bucket-fill src indices ----------------
__global__ void fill_kernel(const int* __restrict__ src, const int* __restrict__ dst,
                            const int* __restrict__ start, int* __restrict__ cursor,
                            int* __restrict__ order, int nE) {
    int e = blockIdx.x * blockDim.x + threadIdx.x;
    if (e >= nE) return;
    int d = dst[e];
    int pos = start[d] + atomicAdd(&cursor[d], 1);
    order[pos] = src[e];
}

// ---------------- Phase D: gather-reduce -> A1 = bf16(x + agg) ----------------
__global__ void gather_agg_kernel(const float* __restrict__ x,
                                  const int* __restrict__ order,
                                  const int* __restrict__ start,
                                  unsigned short* __restrict__ A1, int M) {
    int node = blockIdx.x * 8 + (threadIdx.x >> 5);
    if (node >= M) return;
    int lane = threadIdx.x & 31;
    const float4* xv = (const float4*)x;
    float4 acc = xv[(size_t)node * 32 + lane];  // the "+x" term
    int e0 = start[node], e1 = start[node + 1];
    for (int e = e0; e < e1; ++e) {
        int s = order[e];
        float4 v = xv[(size_t)s * 32 + lane];
        acc.x += v.x; acc.y += v.y; acc.z += v.z; acc.w += v.w;
    }
    ushort4 o;
    o.x = f2bf(acc.x); o.y = f2bf(acc.y); o.z = f2bf(acc.z); o.w = f2bf(acc.w);
    ((ushort4*)A1)[(size_t)node * 32 + lane] = o;
}

// ---------------- all weight transposes in one launch ----------------
// W1t[256][128], W2t[256][256], Wlt[64][256] (zero-padded cols >= 40)
__global__ void wtrans_all_kernel(const float* __restrict__ W1,
                                  const float* __restrict__ W2,
                                  const float* __restrict__ Wl,
                                  unsigned short* __restrict__ W1t,
                                  unsigned short* __restrict__ W2t,
                                  unsigned short* __restrict__ Wlt) {
    int idx = blockIdx.x * 256 + threadIdx.x;
    if (idx < 32768) {                    // W1t: [n=256][k=128]
        int n = idx >> 7, k = idx & 127;
        W1t[idx] = f2bf(W1[k * DIM_H + n]);
    } else if (idx < 32768 + 65536) {     // W2t: [n=256][k=256]
        int i = idx - 32768;
        int n = i >> 8, k = i & 255;
        W2t[i] = f2bf(W2[k * DIM_H + n]);
    } else if (idx < 32768 + 65536 + 16384) {  // Wlt: [n=64][k=256]
        int i = idx - 98304;
        int n = i >> 8, k = i & 255;
        Wlt[i] = f2bf((n < N_CLASSES) ? Wl[k * N_CLASSES + n] : 0.f);
    }
}

// ---------------- BN reduce: partials[R][512] -> scale/shift ----------------
__global__ void bn_reduce_kernel(const float* __restrict__ partials, int R,
                                 const float* __restrict__ gamma,
                                 const float* __restrict__ beta,
                                 float* __restrict__ scale,
                                 float* __restrict__ shift, int M) {
    __shared__ float ls[256], lss[256];
    int c = blockIdx.x, t = threadIdx.x;
    float s = 0.f, ss = 0.f;
    for (int r = t; r < R; r += 256) {
        s += partials[(long)r * 512 + c];
        ss += partials[(long)r * 512 + 256 + c];
    }
    ls[t] = s; lss[t] = ss;
    __syncthreads();
    for (int o = 128; o > 0; o >>= 1) {
        if (t < o) { ls[t] += ls[t + o]; lss[t] += lss[t + o]; }
        __syncthreads();
    }
    if (t == 0) {
        float inv = 1.0f / (float)M;
        float mean = ls[0] * inv;
        float var = lss[0] * inv - mean * mean;
        float sc = gamma[c] * rsqrtf(var + BN_EPS);
        scale[c] = sc;
        shift[c] = beta[c] - mean * sc;
    }
}

// ---------------- MFMA GEMM ----------------
// MODE 0: bf16 out + per-wave BN column partial sums (atomic-free)
// MODE 1: A-fragments get relu(a*scale[k]+shift[k]) inline; relu->bf16 out
// MODE 2: fp32 out with col < Nout guard (Nout=40)
template <int WM, int WN, int K, int MODE>
__global__ __launch_bounds__(WM* WN * 64) void mfma_gemm(
    const unsigned short* __restrict__ A,  // [M_PAD, K] bf16
    const unsigned short* __restrict__ Bt, // [Npad, K] bf16 (N-major, K-contig)
    const float* __restrict__ bias,
    void* __restrict__ Cout,
    const float* __restrict__ scale,
    const float* __restrict__ shift,
    float* __restrict__ partials,
    int M, int Nout) {
    const int BM = WM * 64, BN = WN * 64;
    int wave = threadIdx.x >> 6;
    int lane = threadIdx.x & 63;
    int wm = wave / WN, wn = wave % WN;
    int l15 = lane & 15, q = lane >> 4;
    long row0 = (long)blockIdx.y * BM + wm * 64;
    long col0 = (long)blockIdx.x * BN + wn * 64;

    f32x4 acc[4][4] = {};
    const unsigned short* Ap = A + (row0 + l15) * K + q * 8;
    const unsigned short* Bp = Bt + (col0 + l15) * K + q * 8;

#pragma unroll
    for (int kk = 0; kk < K; kk += 32) {
        bf16x8 af[4], bfr[4];
#pragma unroll
        for (int mt = 0; mt < 4; ++mt)
            af[mt] = *(const bf16x8*)(Ap + (long)mt * 16 * K + kk);
#pragma unroll
        for (int nt = 0; nt < 4; ++nt)
            bfr[nt] = *(const bf16x8*)(Bp + (long)nt * 16 * K + kk);
        if (MODE == 1) {
            // fused BN + ReLU on A fragments: k = kk + q*8 + j
            float sc[8], sh[8];
#pragma unroll
            for (int j = 0; j < 8; ++j) {
                sc[j] = scale[kk + q * 8 + j];
                sh[j] = shift[kk + q * 8 + j];
            }
#pragma unroll
            for (int mt = 0; mt < 4; ++mt) {
#pragma unroll
                for (int j = 0; j < 8; ++j) {
                    float f = bf2f((unsigned short)af[mt][j]);
                    f = fmaxf(f * sc[j] + sh[j], 0.f);
                    af[mt][j] = (short)f2bf(f);
                }
            }
        }
#pragma unroll
        for (int mt = 0; mt < 4; ++mt)
#pragma unroll
            for (int nt = 0; nt < 4; ++nt)
                acc[mt][nt] = __builtin_amdgcn_mfma_f32_16x16x32_bf16(
                    af[mt], bfr[nt], acc[mt][nt], 0, 0, 0);
    }

#pragma unroll
    for (int nt = 0; nt < 4; ++nt) {
        long col = col0 + nt * 16 + l15;
        float b = (MODE == 2) ? ((col < Nout) ? bias[col] : 0.f) : bias[col];
        float s = 0.f, ss = 0.f;
#pragma unroll
        for (int mt = 0; mt < 4; ++mt) {
#pragma unroll
            for (int r = 0; r < 4; ++r) {
                long row = row0 + mt * 16 + q * 4 + r;
                float v = acc[mt][nt][r] + b;
                if (row < M) {
                    if (MODE == 0) {
                        ((unsigned short*)Cout)[row * DIM_H + col] = f2bf(v);
                        s += v; ss += v * v;
                    } else if (MODE == 1) {
                        ((unsigned short*)Cout)[row * DIM_H + col] = f2bf(fmaxf(v, 0.f));
                    } else {
                        if (col < Nout) ((float*)Cout)[row * Nout + col] = v;
                    }
                }
            }
        }
        if (MODE == 0) {
            // reduce over q (4 quads) -> lanes 0..15 hold full column sums
            s += __shfl_xor(s, 16, 64);  s += __shfl_xor(s, 32, 64);
            ss += __shfl_xor(ss, 16, 64); ss += __shfl_xor(ss, 32, 64);
            if (lane < 16) {
                long pr = (long)blockIdx.y * WM + wm;
                partials[pr * 512 + col] = s;
                partials[pr * 512 + 256 + col] = ss;
            }
        }
    }
}

extern "C" void kernel_launch(void* const* d_in, const int* in_sizes, int n_in,
                              void* d_out, int out_size, void* d_ws, size_t ws_size,
                              hipStream_t stream) {
    const float* x     = (const float*)d_in[0];
    const int*   ei    = (const int*)d_in[1];
    const float* W1    = (const float*)d_in[2];
    const float* b1    = (const float*)d_in[3];
    const float* gamma = (const float*)d_in[4];
    const float* beta  = (const float*)d_in[5];
    const float* W2    = (const float*)d_in[6];
    const float* b2    = (const float*)d_in[7];
    const float* Wlin  = (const float*)d_in[8];
    const float* blin  = (const float*)d_in[9];
    float* out = (float*)d_out;

    int M  = in_sizes[0] / F_IN;  // 50000
    int nE = in_sizes[1] / 2;     // 600000
    const int* srcIdx = ei;
    const int* dstIdx = ei + nE;
    int nB = (M + 255) / 256;         // scan blocks
    int g1y = (M + 127) / 128;        // GEMM1/2 y-blocks (covers M, <= M_PAD)
    int Rpart = g1y * 2;              // partials rows (WM=2)

    // ---- workspace layout ----
    unsigned short* A1bf  = (unsigned short*)d_ws;                     // M_PAD*128 bf16
    unsigned short* h1bf  = A1bf + (size_t)M_PAD * F_IN;               // M_PAD*256 bf16
    unsigned short* h2bf  = h1bf + (size_t)M_PAD * DIM_H;              // M_PAD*256 bf16
    unsigned short* W1t   = h2bf + (size_t)M_PAD * DIM_H;              // 256*128
    unsigned short* W2t   = W1t + DIM_H * F_IN;                        // 256*256
    unsigned short* Wlt   = W2t + DIM_H * DIM_H;                       // 64*256
    float*          partials = (float*)(Wlt + 64 * DIM_H);             // Rpart*512
    float*          scale = partials + (size_t)800 * 512;              // 256
    float*          shift = scale + DIM_H;                             // 256
    int*            hist  = (int*)(shift + DIM_H);                     // M
    int*            cursor= hist + M;                                  // M (adjacent -> one memset)
    int*            start = cursor + M;                                // M+1
    int*            blockSums = start + (M + 1);                       // 256
    int*            blockOffs = blockSums + 256;                       // 256
    int*            order = blockOffs + 256;                           // nE

    hipMemsetAsync(hist, 0, (size_t)2 * M * sizeof(int), stream);  // hist + cursor

    int tB = 256;
    hist_kernel<<<(nE + tB - 1) / tB, tB, 0, stream>>>(dstIdx, hist, nE);
    scan_blocks_kernel<<<nB, 256, 0, stream>>>(hist, blockSums, M);
    scan_offsets_kernel<<<1, 256, 0, stream>>>(blockSums, blockOffs, nB, start, M, nE);
    scan_final_kernel<<<nB, 256, 0, stream>>>(hist, blockOffs, start, M);
    fill_kernel<<<(nE + tB - 1) / tB, tB, 0, stream>>>(srcIdx, dstIdx, start, cursor, order, nE);
    gather_agg_kernel<<<(M + 7) / 8, 256, 0, stream>>>(x, order, start, A1bf, M);
    wtrans_all_kernel<<<(32768 + 65536 + 16384) / 256, 256, 0, stream>>>(
        W1, W2, Wlin, W1t, W2t, Wlt);

    // GEMM1: h1 = bf16(A1 @ W1 + b1), atomic-free BN partials. 128x256 block, 8 waves.
    mfma_gemm<2, 4, F_IN, 0><<<dim3(1, g1y), 512, 0, stream>>>(
        A1bf, W1t, b1, h1bf, nullptr, nullptr, partials, M, DIM_H);
    bn_reduce_kernel<<<DIM_H, 256, 0, stream>>>(partials, Rpart, gamma, beta, scale, shift, M);
    // GEMM2: h2 = relu( relu(bn(h1)) @ W2 + b2 ) -> bf16, BN fused into A-load
    mfma_gemm<2, 2, DIM_H, 1><<<dim3(2, g1y), 256, 0, stream>>>(
        h1bf, W2t, b2, h2bf, scale, shift, nullptr, M, DIM_H);
    // GEMM3: out = h2 @ Wlin + blin (fp32, col<40)
    mfma_gemm<4, 1, DIM_H, 2><<<dim3(1, (M + 255) / 256), 256, 0, stream>>>(
        h2bf, Wlt, blin, out, nullptr, nullptr, nullptr, M, N_CLASSES);
}

// Round 6
// 287.507 us; speedup vs baseline: 4.9645x; 1.0725x over previous
//
#include <hip/hip_runtime.h>

#define F_IN 128
#define DIM_H 256
#define N_CLASSES 40
#define BN_EPS 1e-5f
#define M_PAD 50176  // ceil(50000/256)*256 — max padded rows any GEMM touches

typedef short bf16x8 __attribute__((ext_vector_type(8)));
typedef float f32x4 __attribute__((ext_vector_type(4)));

__device__ __forceinline__ unsigned short f2bf(float f) {
    union { float f; unsigned u; } v; v.f = f;
    unsigned r = v.u + 0x7fff + ((v.u >> 16) & 1);  // RNE
    return (unsigned short)(r >> 16);
}
__device__ __forceinline__ float bf2f(unsigned short u) {
    union { unsigned u; float f; } v; v.u = ((unsigned)u) << 16;
    return v.f;
}

// ---------------- Phase A: histogram of dst ----------------
__global__ void hist_kernel(const int* __restrict__ dst, int* __restrict__ hist, int nE) {
    int e = blockIdx.x * blockDim.x + threadIdx.x;
    if (e >= nE) return;
    atomicAdd(&hist[dst[e]], 1);
}

// ---------------- Phase B: hierarchical exclusive scan ----------------
__global__ void scan_blocks_kernel(const int* __restrict__ hist,
                                   int* __restrict__ blockSums, int M) {
    __shared__ int lds[256];
    int t = threadIdx.x;
    int i = blockIdx.x * 256 + t;
    lds[t] = (i < M) ? hist[i] : 0;
    __syncthreads();
    for (int off = 128; off > 0; off >>= 1) {
        if (t < off) lds[t] += lds[t + off];
        __syncthreads();
    }
    if (t == 0) blockSums[blockIdx.x] = lds[0];
}

__global__ void scan_offsets_kernel(const int* __restrict__ blockSums,
                                    int* __restrict__ blockOffs,
                                    int nB, int* __restrict__ start, int M, int nE) {
    __shared__ int lds[256];
    int t = threadIdx.x;
    int orig = (t < nB) ? blockSums[t] : 0;
    lds[t] = orig;
    __syncthreads();
    for (int off = 1; off < 256; off <<= 1) {
        int v = (t >= off) ? lds[t - off] : 0;
        __syncthreads();
        lds[t] += v;
        __syncthreads();
    }
    if (t < nB) blockOffs[t] = lds[t] - orig;
    if (t == 0) start[M] = nE;
}

__global__ void scan_final_kernel(const int* __restrict__ hist,
                                  const int* __restrict__ blockOffs,
                                  int* __restrict__ start, int M) {
    __shared__ int lds[256];
    int t = threadIdx.x;
    int i = blockIdx.x * 256 + t;
    int orig = (i < M) ? hist[i] : 0;
    lds[t] = orig;
    __syncthreads();
    for (int off = 1; off < 256; off <<= 1) {
        int v = (t >= off) ? lds[t - off] : 0;
        __syncthreads();
        lds[t] += v;
        __syncthreads();
    }
    if (i < M) start[i] = blockOffs[blockIdx.x] + lds[t] - orig;
}

// ---------------- Phase C: bucket-fill src indices ----------------
__global__ void fill_kernel(const int* __restrict__ src, const int* __restrict__ dst,
                            const int* __restrict__ start, int* __restrict__ cursor,
                            int* __restrict__ order, int nE) {
    int e = blockIdx.x * blockDim.x + threadIdx.x;
    if (e >= nE) return;
    int d = dst[e];
    int pos = start[d] + atomicAdd(&cursor[d], 1);
    order[pos] = src[e];
}

// ---------------- Phase D: gather-reduce -> A1 = bf16(x + agg) ----------------
__global__ void gather_agg_kernel(const float* __restrict__ x,
                                  const int* __restrict__ order,
                                  const int* __restrict__ start,
                                  unsigned short* __restrict__ A1, int M) {
    int node = blockIdx.x * 8 + (threadIdx.x >> 5);
    if (node >= M) return;
    int lane = threadIdx.x & 31;
    const float4* xv = (const float4*)x;
    float4 acc = xv[(size_t)node * 32 + lane];  // the "+x" term
    int e0 = start[node], e1 = start[node + 1];
    for (int e = e0; e < e1; ++e) {
        int s = order[e];
        float4 v = xv[(size_t)s * 32 + lane];
        acc.x += v.x; acc.y += v.y; acc.z += v.z; acc.w += v.w;
    }
    ushort4 o;
    o.x = f2bf(acc.x); o.y = f2bf(acc.y); o.z = f2bf(acc.z); o.w = f2bf(acc.w);
    ((ushort4*)A1)[(size_t)node * 32 + lane] = o;
}

// ---------------- all weight transposes in one launch ----------------
__global__ void wtrans_all_kernel(const float* __restrict__ W1,
                                  const float* __restrict__ W2,
                                  const float* __restrict__ Wl,
                                  unsigned short* __restrict__ W1t,
                                  unsigned short* __restrict__ W2t,
                                  unsigned short* __restrict__ Wlt) {
    int idx = blockIdx.x * 256 + threadIdx.x;
    if (idx < 32768) {                    // W1t: [n=256][k=128]
        int n = idx >> 7, k = idx & 127;
        W1t[idx] = f2bf(W1[k * DIM_H + n]);
    } else if (idx < 32768 + 65536) {     // W2t: [n=256][k=256]
        int i = idx - 32768;
        int n = i >> 8, k = i & 255;
        W2t[i] = f2bf(W2[k * DIM_H + n]);
    } else if (idx < 32768 + 65536 + 16384) {  // Wlt: [n=64][k=256]
        int i = idx - 98304;
        int n = i >> 8, k = i & 255;
        Wlt[i] = f2bf((n < N_CLASSES) ? Wl[k * N_CLASSES + n] : 0.f);
    }
}

// ---------------- BN reduce: partials[R][512] -> scale/shift ----------------
__global__ void bn_reduce_kernel(const float* __restrict__ partials, int R,
                                 const float* __restrict__ gamma,
                                 const float* __restrict__ beta,
                                 float* __restrict__ scale,
                                 float* __restrict__ shift, int M) {
    __shared__ float ls[256], lss[256];
    int c = blockIdx.x, t = threadIdx.x;
    float s = 0.f, ss = 0.f;
    for (int r = t; r < R; r += 256) {
        s += partials[(long)r * 512 + c];
        ss += partials[(long)r * 512 + 256 + c];
    }
    ls[t] = s; lss[t] = ss;
    __syncthreads();
    for (int o = 128; o > 0; o >>= 1) {
        if (t < o) { ls[t] += ls[t + o]; lss[t] += lss[t + o]; }
        __syncthreads();
    }
    if (t == 0) {
        float inv = 1.0f / (float)M;
        float mean = ls[0] * inv;
        float var = lss[0] * inv - mean * mean;
        float sc = gamma[c] * rsqrtf(var + BN_EPS);
        scale[c] = sc;
        shift[c] = beta[c] - mean * sc;
    }
}

// ---------------- MFMA GEMM, LDS-staged + double-buffered ----------------
// Block: 256 threads = 4 waves (WM x WN), tile BM=WM*64 x BN=WN*64, BK=32.
// LDS rows padded to 40 ushorts (80 B) -> <=2-way bank aliasing on ds_read_b128 (free).
// MODE 0: bf16 out + per-wave BN column partials (GEMM1)
// MODE 1: BN+ReLU applied to A during staging; relu->bf16 out (GEMM2)
// MODE 2: fp32 out with col < Nout guard (GEMM3)
template <int WM, int WN, int K, int MODE>
__global__ __launch_bounds__(256) void mfma_gemm(
    const unsigned short* __restrict__ A,  // [M_PAD, K] bf16 row-major
    const unsigned short* __restrict__ Bt, // [Npad, K] bf16 row-major (N-major)
    const float* __restrict__ bias,
    void* __restrict__ Cout,
    const float* __restrict__ scale,
    const float* __restrict__ shift,
    float* __restrict__ partials,
    int M, int Nout) {
    constexpr int BM = WM * 64, BN = WN * 64;
    constexpr int S = K / 32;          // K-steps
    constexpr int PITCH = 40;          // ushorts per LDS row (32 data + 8 pad)
    constexpr int ACH = BM / 64;       // A chunks (bf16x8) per thread per step
    constexpr int BCH = BN / 64;       // B chunks per thread per step

    __shared__ __align__(16) unsigned short As[2][BM * PITCH];
    __shared__ __align__(16) unsigned short Bs[2][BN * PITCH];

    int tid = threadIdx.x;
    int wave = tid >> 6, lane = tid & 63;
    int wm = wave / WN, wn = wave % WN;
    int l15 = lane & 15, q = lane >> 4;
    long row0 = (long)blockIdx.y * BM;
    long col0 = (long)blockIdx.x * BN;

    bf16x8 ar[ACH], br[BCH];

    auto loadAB = [&](int s) {
#pragma unroll
        for (int i = 0; i < ACH; ++i) {
            int ch = tid + i * 256;          // 0..BM*4-1
            int m = ch >> 2, c = ch & 3;
            ar[i] = *(const bf16x8*)(A + (row0 + m) * K + s * 32 + c * 8);
        }
#pragma unroll
        for (int i = 0; i < BCH; ++i) {
            int ch = tid + i * 256;
            int m = ch >> 2, c = ch & 3;
            br[i] = *(const bf16x8*)(Bt + (col0 + m) * K + s * 32 + c * 8);
        }
    };

    auto writeAB = [&](int buf, int s) {
#pragma unroll
        for (int i = 0; i < ACH; ++i) {
            int ch = tid + i * 256;
            int m = ch >> 2, c = ch & 3;
            bf16x8 v = ar[i];
            if (MODE == 1) {  // BN + ReLU during staging (once per element)
                int kb = s * 32 + c * 8;
                float4 sc0 = *(const float4*)(scale + kb);
                float4 sc1 = *(const float4*)(scale + kb + 4);
                float4 sh0 = *(const float4*)(shift + kb);
                float4 sh1 = *(const float4*)(shift + kb + 4);
                float scv[8] = {sc0.x, sc0.y, sc0.z, sc0.w, sc1.x, sc1.y, sc1.z, sc1.w};
                float shv[8] = {sh0.x, sh0.y, sh0.z, sh0.w, sh1.x, sh1.y, sh1.z, sh1.w};
#pragma unroll
                for (int j = 0; j < 8; ++j) {
                    float f = bf2f((unsigned short)v[j]);
                    f = fmaxf(f * scv[j] + shv[j], 0.f);
                    v[j] = (short)f2bf(f);
                }
            }
            *(bf16x8*)(&As[buf][m * PITCH + c * 8]) = v;
        }
#pragma unroll
        for (int i = 0; i < BCH; ++i) {
            int ch = tid + i * 256;
            int m = ch >> 2, c = ch & 3;
            *(bf16x8*)(&Bs[buf][m * PITCH + c * 8]) = br[i];
        }
    };

    f32x4 acc[4][4] = {};

    loadAB(0);
    writeAB(0, 0);
#pragma unroll
    for (int s = 0; s < S; ++s) {
        if (s + 1 < S) loadAB(s + 1);   // issue next-step globals early
        __syncthreads();                 // buf[s&1] visible to all waves
        int buf = s & 1;
        bf16x8 af[4], bfr[4];
#pragma unroll
        for (int mt = 0; mt < 4; ++mt)
            af[mt] = *(const bf16x8*)(&As[buf][(wm * 64 + mt * 16 + l15) * PITCH + q * 8]);
#pragma unroll
        for (int nt = 0; nt < 4; ++nt)
            bfr[nt] = *(const bf16x8*)(&Bs[buf][(wn * 64 + nt * 16 + l15) * PITCH + q * 8]);
#pragma unroll
        for (int mt = 0; mt < 4; ++mt)
#pragma unroll
            for (int nt = 0; nt < 4; ++nt)
                acc[mt][nt] = __builtin_amdgcn_mfma_f32_16x16x32_bf16(
                    af[mt], bfr[nt], acc[mt][nt], 0, 0, 0);
        if (s + 1 < S) writeAB((s + 1) & 1, s + 1);  // waits vmcnt after MFMAs
    }

    // -------- epilogue --------
#pragma unroll
    for (int nt = 0; nt < 4; ++nt) {
        long col = col0 + wn * 64 + nt * 16 + l15;
        float b = (MODE == 2) ? ((col < Nout) ? bias[col] : 0.f) : bias[col];
        float s = 0.f, ss = 0.f;
#pragma unroll
        for (int mt = 0; mt < 4; ++mt) {
#pragma unroll
            for (int r = 0; r < 4; ++r) {
                long row = row0 + wm * 64 + mt * 16 + q * 4 + r;
                float v = acc[mt][nt][r] + b;
                if (row < M) {
                    if (MODE == 0) {
                        ((unsigned short*)Cout)[row * DIM_H + col] = f2bf(v);
                        s += v; ss += v * v;
                    } else if (MODE == 1) {
                        ((unsigned short*)Cout)[row * DIM_H + col] = f2bf(fmaxf(v, 0.f));
                    } else {
                        if (col < Nout) ((float*)Cout)[row * Nout + col] = v;
                    }
                }
            }
        }
        if (MODE == 0) {
            s += __shfl_xor(s, 16, 64);  s += __shfl_xor(s, 32, 64);
            ss += __shfl_xor(ss, 16, 64); ss += __shfl_xor(ss, 32, 64);
            if (lane < 16) {
                long pr = (long)blockIdx.y * WM + wm;
                partials[pr * 512 + col] = s;
                partials[pr * 512 + 256 + col] = ss;
            }
        }
    }
}

extern "C" void kernel_launch(void* const* d_in, const int* in_sizes, int n_in,
                              void* d_out, int out_size, void* d_ws, size_t ws_size,
                              hipStream_t stream) {
    const float* x     = (const float*)d_in[0];
    const int*   ei    = (const int*)d_in[1];
    const float* W1    = (const float*)d_in[2];
    const float* b1    = (const float*)d_in[3];
    const float* gamma = (const float*)d_in[4];
    const float* beta  = (const float*)d_in[5];
    const float* W2    = (const float*)d_in[6];
    const float* b2    = (const float*)d_in[7];
    const float* Wlin  = (const float*)d_in[8];
    const float* blin  = (const float*)d_in[9];
    float* out = (float*)d_out;

    int M  = in_sizes[0] / F_IN;  // 50000
    int nE = in_sizes[1] / 2;     // 600000
    const int* srcIdx = ei;
    const int* dstIdx = ei + nE;
    int nB = (M + 255) / 256;         // scan blocks
    int g12y = (M + 127) / 128;       // GEMM1/2 y-blocks (128-row tiles)
    int g3y  = (M + 255) / 256;       // GEMM3 y-blocks (256-row tiles)
    int Rpart = g12y * 2;             // partials rows (WM=2)

    // ---- workspace layout ----
    unsigned short* A1bf  = (unsigned short*)d_ws;                     // M_PAD*128 bf16
    unsigned short* h1bf  = A1bf + (size_t)M_PAD * F_IN;               // M_PAD*256 bf16
    unsigned short* h2bf  = h1bf + (size_t)M_PAD * DIM_H;              // M_PAD*256 bf16
    unsigned short* W1t   = h2bf + (size_t)M_PAD * DIM_H;              // 256*128
    unsigned short* W2t   = W1t + DIM_H * F_IN;                        // 256*256
    unsigned short* Wlt   = W2t + DIM_H * DIM_H;                       // 64*256
    float*          partials = (float*)(Wlt + 64 * DIM_H);             // Rpart*512
    float*          scale = partials + (size_t)800 * 512;              // 256
    float*          shift = scale + DIM_H;                             // 256
    int*            hist  = (int*)(shift + DIM_H);                     // M
    int*            cursor= hist + M;                                  // M (adjacent -> one memset)
    int*            start = cursor + M;                                // M+1
    int*            blockSums = start + (M + 1);                       // 256
    int*            blockOffs = blockSums + 256;                       // 256
    int*            order = blockOffs + 256;                           // nE

    hipMemsetAsync(hist, 0, (size_t)2 * M * sizeof(int), stream);  // hist + cursor

    int tB = 256;
    hist_kernel<<<(nE + tB - 1) / tB, tB, 0, stream>>>(dstIdx, hist, nE);
    scan_blocks_kernel<<<nB, 256, 0, stream>>>(hist, blockSums, M);
    scan_offsets_kernel<<<1, 256, 0, stream>>>(blockSums, blockOffs, nB, start, M, nE);
    scan_final_kernel<<<nB, 256, 0, stream>>>(hist, blockOffs, start, M);
    fill_kernel<<<(nE + tB - 1) / tB, tB, 0, stream>>>(srcIdx, dstIdx, start, cursor, order, nE);
    gather_agg_kernel<<<(M + 7) / 8, 256, 0, stream>>>(x, order, start, A1bf, M);
    wtrans_all_kernel<<<(32768 + 65536 + 16384) / 256, 256, 0, stream>>>(
        W1, W2, Wlin, W1t, W2t, Wlt);

    // GEMM1: h1 = bf16(A1 @ W1 + b1), atomic-free BN partials
    mfma_gemm<2, 2, F_IN, 0><<<dim3(2, g12y), 256, 0, stream>>>(
        A1bf, W1t, b1, h1bf, nullptr, nullptr, partials, M, DIM_H);
    bn_reduce_kernel<<<DIM_H, 256, 0, stream>>>(partials, Rpart, gamma, beta, scale, shift, M);
    // GEMM2: h2 = relu( relu(bn(h1)) @ W2 + b2 ) -> bf16, BN fused into staging
    mfma_gemm<2, 2, DIM_H, 1><<<dim3(2, g12y), 256, 0, stream>>>(
        h1bf, W2t, b2, h2bf, scale, shift, nullptr, M, DIM_H);
    // GEMM3: out = h2 @ Wlin + blin (fp32, col<40), 256x64 tiles
    mfma_gemm<4, 1, DIM_H, 2><<<dim3(1, g3y), 256, 0, stream>>>(
        h2bf, Wlt, blin, out, nullptr, nullptr, nullptr, M, N_CLASSES);
}

// Round 7
// 271.741 us; speedup vs baseline: 5.2525x; 1.0580x over previous
//
#include <hip/hip_runtime.h>

#define F_IN 128
#define DIM_H 256
#define N_CLASSES 40
#define BN_EPS 1e-5f
#define M_PAD 50176  // ceil(50000/256)*256 — max padded rows any GEMM touches

typedef short bf16x8 __attribute__((ext_vector_type(8)));
typedef float f32x4 __attribute__((ext_vector_type(4)));

__device__ __forceinline__ unsigned short f2bf(float f) {
    union { float f; unsigned u; } v; v.f = f;
    unsigned r = v.u + 0x7fff + ((v.u >> 16) & 1);  // RNE
    return (unsigned short)(r >> 16);
}
__device__ __forceinline__ float bf2f(unsigned short u) {
    union { unsigned u; float f; } v; v.u = ((unsigned)u) << 16;
    return v.f;
}
__device__ __forceinline__ float4 bf2f4(ushort4 u) {
    return make_float4(bf2f(u.x), bf2f(u.y), bf2f(u.z), bf2f(u.w));
}

// ---------------- Phase A: histogram of dst ----------------
__global__ void hist_kernel(const int* __restrict__ dst, int* __restrict__ hist, int nE) {
    int e = blockIdx.x * blockDim.x + threadIdx.x;
    if (e >= nE) return;
    atomicAdd(&hist[dst[e]], 1);
}

// ---------------- Phase B: hierarchical exclusive scan ----------------
__global__ void scan_blocks_kernel(const int* __restrict__ hist,
                                   int* __restrict__ blockSums, int M) {
    __shared__ int lds[256];
    int t = threadIdx.x;
    int i = blockIdx.x * 256 + t;
    lds[t] = (i < M) ? hist[i] : 0;
    __syncthreads();
    for (int off = 128; off > 0; off >>= 1) {
        if (t < off) lds[t] += lds[t + off];
        __syncthreads();
    }
    if (t == 0) blockSums[blockIdx.x] = lds[0];
}

__global__ void scan_offsets_kernel(const int* __restrict__ blockSums,
                                    int* __restrict__ blockOffs,
                                    int nB, int* __restrict__ start, int M, int nE) {
    __shared__ int lds[256];
    int t = threadIdx.x;
    int orig = (t < nB) ? blockSums[t] : 0;
    lds[t] = orig;
    __syncthreads();
    for (int off = 1; off < 256; off <<= 1) {
        int v = (t >= off) ? lds[t - off] : 0;
        __syncthreads();
        lds[t] += v;
        __syncthreads();
    }
    if (t < nB) blockOffs[t] = lds[t] - orig;
    if (t == 0) start[M] = nE;
}

__global__ void scan_final_kernel(const int* __restrict__ hist,
                                  const int* __restrict__ blockOffs,
                                  int* __restrict__ start, int M) {
    __shared__ int lds[256];
    int t = threadIdx.x;
    int i = blockIdx.x * 256 + t;
    int orig = (i < M) ? hist[i] : 0;
    lds[t] = orig;
    __syncthreads();
    for (int off = 1; off < 256; off <<= 1) {
        int v = (t >= off) ? lds[t - off] : 0;
        __syncthreads();
        lds[t] += v;
        __syncthreads();
    }
    if (i < M) start[i] = blockOffs[blockIdx.x] + lds[t] - orig;
}

// ---------------- Phase C: bucket-fill src indices ----------------
__global__ void fill_kernel(const int* __restrict__ src, const int* __restrict__ dst,
                            const int* __restrict__ start, int* __restrict__ cursor,
                            int* __restrict__ order, int nE) {
    int e = blockIdx.x * blockDim.x + threadIdx.x;
    if (e >= nE) return;
    int d = dst[e];
    int pos = start[d] + atomicAdd(&cursor[d], 1);
    order[pos] = src[e];
}

// ---------------- prep: xb = bf16(x)  +  all weight transposes ----------------
// jobs [0, XQ): float4 -> ushort4 cast of x (XQ = M*32 quads)
// jobs [XQ, XQ+114688): weight transpose singles
__global__ void prep_kernel(const float* __restrict__ x, unsigned short* __restrict__ xb,
                            const float* __restrict__ W1, const float* __restrict__ W2,
                            const float* __restrict__ Wl,
                            unsigned short* __restrict__ W1t,
                            unsigned short* __restrict__ W2t,
                            unsigned short* __restrict__ Wlt, int XQ) {
    int idx = blockIdx.x * 256 + threadIdx.x;
    if (idx < XQ) {
        float4 v = ((const float4*)x)[idx];
        ushort4 o;
        o.x = f2bf(v.x); o.y = f2bf(v.y); o.z = f2bf(v.z); o.w = f2bf(v.w);
        ((ushort4*)xb)[idx] = o;
        return;
    }
    int j = idx - XQ;
    if (j < 32768) {                    // W1t: [n=256][k=128]
        int n = j >> 7, k = j & 127;
        W1t[j] = f2bf(W1[k * DIM_H + n]);
    } else if (j < 32768 + 65536) {     // W2t: [n=256][k=256]
        int i = j - 32768;
        int n = i >> 8, k = i & 255;
        W2t[i] = f2bf(W2[k * DIM_H + n]);
    } else if (j < 32768 + 65536 + 16384) {  // Wlt: [n=64][k=256]
        int i = j - 98304;
        int n = i >> 8, k = i & 255;
        Wlt[i] = f2bf((n < N_CLASSES) ? Wl[k * N_CLASSES + n] : 0.f);
    }
}

// ---------------- Phase D: gather-reduce (bf16 rows) -> A1 = bf16(x + agg) ----------------
// half-wave (32 lanes) per node; neighbor rows bf16 (256 B), self row fp32.
// 4-wide edge unroll with independent accumulators for MLP.
__global__ void gather_agg_kernel(const float* __restrict__ x,
                                  const unsigned short* __restrict__ xb,
                                  const int* __restrict__ order,
                                  const int* __restrict__ start,
                                  unsigned short* __restrict__ A1, int M) {
    int node = blockIdx.x * 8 + (threadIdx.x >> 5);
    if (node >= M) return;
    int lane = threadIdx.x & 31;
    const ushort4* xv = (const ushort4*)xb;
    float4 a0 = ((const float4*)x)[(size_t)node * 32 + lane];  // self term, fp32
    float4 a1 = make_float4(0.f, 0.f, 0.f, 0.f);
    float4 a2 = a1, a3 = a1;
    int e0 = start[node], e1 = start[node + 1];
    int e = e0;
    for (; e + 4 <= e1; e += 4) {
        int s0 = order[e], s1 = order[e + 1], s2 = order[e + 2], s3 = order[e + 3];
        float4 v0 = bf2f4(xv[(size_t)s0 * 32 + lane]);
        float4 v1 = bf2f4(xv[(size_t)s1 * 32 + lane]);
        float4 v2 = bf2f4(xv[(size_t)s2 * 32 + lane]);
        float4 v3 = bf2f4(xv[(size_t)s3 * 32 + lane]);
        a0.x += v0.x; a0.y += v0.y; a0.z += v0.z; a0.w += v0.w;
        a1.x += v1.x; a1.y += v1.y; a1.z += v1.z; a1.w += v1.w;
        a2.x += v2.x; a2.y += v2.y; a2.z += v2.z; a2.w += v2.w;
        a3.x += v3.x; a3.y += v3.y; a3.z += v3.z; a3.w += v3.w;
    }
    for (; e < e1; ++e) {
        float4 v = bf2f4(xv[(size_t)order[e] * 32 + lane]);
        a1.x += v.x; a1.y += v.y; a1.z += v.z; a1.w += v.w;
    }
    float4 t;
    t.x = (a0.x + a1.x) + (a2.x + a3.x);
    t.y = (a0.y + a1.y) + (a2.y + a3.y);
    t.z = (a0.z + a1.z) + (a2.z + a3.z);
    t.w = (a0.w + a1.w) + (a2.w + a3.w);
    ushort4 o;
    o.x = f2bf(t.x); o.y = f2bf(t.y); o.z = f2bf(t.z); o.w = f2bf(t.w);
    ((ushort4*)A1)[(size_t)node * 32 + lane] = o;
}

// ---------------- BN reduce: partials[R][512] -> scale/shift ----------------
__global__ void bn_reduce_kernel(const float* __restrict__ partials, int R,
                                 const float* __restrict__ gamma,
                                 const float* __restrict__ beta,
                                 float* __restrict__ scale,
                                 float* __restrict__ shift, int M) {
    __shared__ float ls[256], lss[256];
    int c = blockIdx.x, t = threadIdx.x;
    float s = 0.f, ss = 0.f;
    for (int r = t; r < R; r += 256) {
        s += partials[(long)r * 512 + c];
        ss += partials[(long)r * 512 + 256 + c];
    }
    ls[t] = s; lss[t] = ss;
    __syncthreads();
    for (int o = 128; o > 0; o >>= 1) {
        if (t < o) { ls[t] += ls[t + o]; lss[t] += lss[t + o]; }
        __syncthreads();
    }
    if (t == 0) {
        float inv = 1.0f / (float)M;
        float mean = ls[0] * inv;
        float var = lss[0] * inv - mean * mean;
        float sc = gamma[c] * rsqrtf(var + BN_EPS);
        scale[c] = sc;
        shift[c] = beta[c] - mean * sc;
    }
}

// ---------------- MFMA GEMM, LDS-staged + double-buffered ----------------
// MODE 0: bf16 out + per-wave BN column partials (GEMM1)
// MODE 1: BN+ReLU applied to A during staging; relu->bf16 out (GEMM2)
// MODE 2: fp32 out with col < Nout guard (GEMM3)
template <int WM, int WN, int K, int MODE>
__global__ __launch_bounds__(256) void mfma_gemm(
    const unsigned short* __restrict__ A,  // [M_PAD, K] bf16 row-major
    const unsigned short* __restrict__ Bt, // [Npad, K] bf16 row-major (N-major)
    const float* __restrict__ bias,
    void* __restrict__ Cout,
    const float* __restrict__ scale,
    const float* __restrict__ shift,
    float* __restrict__ partials,
    int M, int Nout) {
    constexpr int BM = WM * 64, BN = WN * 64;
    constexpr int S = K / 32;          // K-steps
    constexpr int PITCH = 40;          // ushorts per LDS row (32 data + 8 pad)
    constexpr int ACH = BM / 64;       // A chunks (bf16x8) per thread per step
    constexpr int BCH = BN / 64;       // B chunks per thread per step

    __shared__ __align__(16) unsigned short As[2][BM * PITCH];
    __shared__ __align__(16) unsigned short Bs[2][BN * PITCH];

    int tid = threadIdx.x;
    int wave = tid >> 6, lane = tid & 63;
    int wm = wave / WN, wn = wave % WN;
    int l15 = lane & 15, q = lane >> 4;
    long row0 = (long)blockIdx.y * BM;
    long col0 = (long)blockIdx.x * BN;

    bf16x8 ar[ACH], br[BCH];

    auto loadAB = [&](int s) {
#pragma unroll
        for (int i = 0; i < ACH; ++i) {
            int ch = tid + i * 256;
            int m = ch >> 2, c = ch & 3;
            ar[i] = *(const bf16x8*)(A + (row0 + m) * K + s * 32 + c * 8);
        }
#pragma unroll
        for (int i = 0; i < BCH; ++i) {
            int ch = tid + i * 256;
            int m = ch >> 2, c = ch & 3;
            br[i] = *(const bf16x8*)(Bt + (col0 + m) * K + s * 32 + c * 8);
        }
    };

    auto writeAB = [&](int buf, int s) {
#pragma unroll
        for (int i = 0; i < ACH; ++i) {
            int ch = tid + i * 256;
            int m = ch >> 2, c = ch & 3;
            bf16x8 v = ar[i];
            if (MODE == 1) {  // BN + ReLU during staging (once per element)
                int kb = s * 32 + c * 8;
                float4 sc0 = *(const float4*)(scale + kb);
                float4 sc1 = *(const float4*)(scale + kb + 4);
                float4 sh0 = *(const float4*)(shift + kb);
                float4 sh1 = *(const float4*)(shift + kb + 4);
                float scv[8] = {sc0.x, sc0.y, sc0.z, sc0.w, sc1.x, sc1.y, sc1.z, sc1.w};
                float shv[8] = {sh0.x, sh0.y, sh0.z, sh0.w, sh1.x, sh1.y, sh1.z, sh1.w};
#pragma unroll
                for (int j = 0; j < 8; ++j) {
                    float f = bf2f((unsigned short)v[j]);
                    f = fmaxf(f * scv[j] + shv[j], 0.f);
                    v[j] = (short)f2bf(f);
                }
            }
            *(bf16x8*)(&As[buf][m * PITCH + c * 8]) = v;
        }
#pragma unroll
        for (int i = 0; i < BCH; ++i) {
            int ch = tid + i * 256;
            int m = ch >> 2, c = ch & 3;
            *(bf16x8*)(&Bs[buf][m * PITCH + c * 8]) = br[i];
        }
    };

    f32x4 acc[4][4] = {};

    loadAB(0);
    writeAB(0, 0);
#pragma unroll
    for (int s = 0; s < S; ++s) {
        if (s + 1 < S) loadAB(s + 1);   // issue next-step globals early
        __syncthreads();
        int buf = s & 1;
        bf16x8 af[4], bfr[4];
#pragma unroll
        for (int mt = 0; mt < 4; ++mt)
            af[mt] = *(const bf16x8*)(&As[buf][(wm * 64 + mt * 16 + l15) * PITCH + q * 8]);
#pragma unroll
        for (int nt = 0; nt < 4; ++nt)
            bfr[nt] = *(const bf16x8*)(&Bs[buf][(wn * 64 + nt * 16 + l15) * PITCH + q * 8]);
#pragma unroll
        for (int mt = 0; mt < 4; ++mt)
#pragma unroll
            for (int nt = 0; nt < 4; ++nt)
                acc[mt][nt] = __builtin_amdgcn_mfma_f32_16x16x32_bf16(
                    af[mt], bfr[nt], acc[mt][nt], 0, 0, 0);
        if (s + 1 < S) writeAB((s + 1) & 1, s + 1);
    }

    // -------- epilogue --------
#pragma unroll
    for (int nt = 0; nt < 4; ++nt) {
        long col = col0 + wn * 64 + nt * 16 + l15;
        float b = (MODE == 2) ? ((col < Nout) ? bias[col] : 0.f) : bias[col];
        float s = 0.f, ss = 0.f;
#pragma unroll
        for (int mt = 0; mt < 4; ++mt) {
#pragma unroll
            for (int r = 0; r < 4; ++r) {
                long row = row0 + wm * 64 + mt * 16 + q * 4 + r;
                float v = acc[mt][nt][r] + b;
                if (row < M) {
                    if (MODE == 0) {
                        ((unsigned short*)Cout)[row * DIM_H + col] = f2bf(v);
                        s += v; ss += v * v;
                    } else if (MODE == 1) {
                        ((unsigned short*)Cout)[row * DIM_H + col] = f2bf(fmaxf(v, 0.f));
                    } else {
                        if (col < Nout) ((float*)Cout)[row * Nout + col] = v;
                    }
                }
            }
        }
        if (MODE == 0) {
            s += __shfl_xor(s, 16, 64);  s += __shfl_xor(s, 32, 64);
            ss += __shfl_xor(ss, 16, 64); ss += __shfl_xor(ss, 32, 64);
            if (lane < 16) {
                long pr = (long)blockIdx.y * WM + wm;
                partials[pr * 512 + col] = s;
                partials[pr * 512 + 256 + col] = ss;
            }
        }
    }
}

extern "C" void kernel_launch(void* const* d_in, const int* in_sizes, int n_in,
                              void* d_out, int out_size, void* d_ws, size_t ws_size,
                              hipStream_t stream) {
    const float* x     = (const float*)d_in[0];
    const int*   ei    = (const int*)d_in[1];
    const float* W1    = (const float*)d_in[2];
    const float* b1    = (const float*)d_in[3];
    const float* gamma = (const float*)d_in[4];
    const float* beta  = (const float*)d_in[5];
    const float* W2    = (const float*)d_in[6];
    const float* b2    = (const float*)d_in[7];
    const float* Wlin  = (const float*)d_in[8];
    const float* blin  = (const float*)d_in[9];
    float* out = (float*)d_out;

    int M  = in_sizes[0] / F_IN;  // 50000
    int nE = in_sizes[1] / 2;     // 600000
    const int* srcIdx = ei;
    const int* dstIdx = ei + nE;
    int nB = (M + 255) / 256;         // scan blocks
    int g12y = (M + 127) / 128;       // GEMM1/2 y-blocks
    int g3y  = (M + 255) / 256;       // GEMM3 y-blocks
    int Rpart = g12y * 2;             // partials rows (WM=2)
    int XQ = M * 32;                  // x float4-quads

    // ---- workspace layout ----
    unsigned short* A1bf  = (unsigned short*)d_ws;                     // M_PAD*128 bf16
    unsigned short* h1bf  = A1bf + (size_t)M_PAD * F_IN;               // M_PAD*256 bf16
    unsigned short* h2bf  = h1bf + (size_t)M_PAD * DIM_H;              // M_PAD*256 bf16
    unsigned short* xb    = h2bf + (size_t)M_PAD * DIM_H;              // M_PAD*128 bf16
    unsigned short* W1t   = xb + (size_t)M_PAD * F_IN;                 // 256*128
    unsigned short* W2t   = W1t + DIM_H * F_IN;                        // 256*256
    unsigned short* Wlt   = W2t + DIM_H * DIM_H;                       // 64*256
    float*          partials = (float*)(Wlt + 64 * DIM_H);             // Rpart*512
    float*          scale = partials + (size_t)800 * 512;              // 256
    float*          shift = scale + DIM_H;                             // 256
    int*            hist  = (int*)(shift + DIM_H);                     // M
    int*            cursor= hist + M;                                  // M
    int*            start = cursor + M;                                // M+1
    int*            blockSums = start + (M + 1);                       // 256
    int*            blockOffs = blockSums + 256;                       // 256
    int*            order = blockOffs + 256;                           // nE

    hipMemsetAsync(hist, 0, (size_t)2 * M * sizeof(int), stream);  // hist + cursor

    int tB = 256;
    hist_kernel<<<(nE + tB - 1) / tB, tB, 0, stream>>>(dstIdx, hist, nE);
    scan_blocks_kernel<<<nB, 256, 0, stream>>>(hist, blockSums, M);
    scan_offsets_kernel<<<1, 256, 0, stream>>>(blockSums, blockOffs, nB, start, M, nE);
    scan_final_kernel<<<nB, 256, 0, stream>>>(hist, blockOffs, start, M);
    fill_kernel<<<(nE + tB - 1) / tB, tB, 0, stream>>>(srcIdx, dstIdx, start, cursor, order, nE);
    prep_kernel<<<(XQ + 114688 + 255) / 256, 256, 0, stream>>>(
        x, xb, W1, W2, Wlin, W1t, W2t, Wlt, XQ);
    gather_agg_kernel<<<(M + 7) / 8, 256, 0, stream>>>(x, xb, order, start, A1bf, M);

    // GEMM1: h1 = bf16(A1 @ W1 + b1), atomic-free BN partials
    mfma_gemm<2, 2, F_IN, 0><<<dim3(2, g12y), 256, 0, stream>>>(
        A1bf, W1t, b1, h1bf, nullptr, nullptr, partials, M, DIM_H);
    bn_reduce_kernel<<<DIM_H, 256, 0, stream>>>(partials, Rpart, gamma, beta, scale, shift, M);
    // GEMM2: h2 = relu( relu(bn(h1)) @ W2 + b2 ) -> bf16, BN fused into staging
    mfma_gemm<2, 2, DIM_H, 1><<<dim3(2, g12y), 256, 0, stream>>>(
        h1bf, W2t, b2, h2bf, scale, shift, nullptr, M, DIM_H);
    // GEMM3: out = h2 @ Wlin + blin (fp32, col<40), 256x64 tiles
    mfma_gemm<4, 1, DIM_H, 2><<<dim3(1, g3y), 256, 0, stream>>>(
        h2bf, Wlt, blin, out, nullptr, nullptr, nullptr, M, N_CLASSES);
}

// Round 8
// 251.955 us; speedup vs baseline: 5.6650x; 1.0785x over previous
//
#include <hip/hip_runtime.h>

#define F_IN 128
#define DIM_H 256
#define N_CLASSES 40
#define BN_EPS 1e-5f
#define M_PAD 50176

typedef short bf16x8 __attribute__((ext_vector_type(8)));
typedef float f32x4 __attribute__((ext_vector_type(4)));

__device__ __forceinline__ unsigned short f2bf(float f) {
    union { float f; unsigned u; } v; v.f = f;
    unsigned r = v.u + 0x7fff + ((v.u >> 16) & 1);  // RNE
    return (unsigned short)(r >> 16);
}
__device__ __forceinline__ float bf2f(unsigned short u) {
    union { unsigned u; float f; } v; v.u = ((unsigned)u) << 16;
    return v.f;
}
__device__ __forceinline__ float4 bf2f4(ushort4 u) {
    return make_float4(bf2f(u.x), bf2f(u.y), bf2f(u.z), bf2f(u.w));
}

// ---------------- Phase A: histogram of dst ----------------
__global__ void hist_kernel(const int* __restrict__ dst, int* __restrict__ hist, int nE) {
    int e = blockIdx.x * blockDim.x + threadIdx.x;
    if (e >= nE) return;
    atomicAdd(&hist[dst[e]], 1);
}

// ---------------- Phase B: hierarchical exclusive scan ----------------
__global__ void scan_blocks_kernel(const int* __restrict__ hist,
                                   int* __restrict__ blockSums, int M) {
    __shared__ int lds[256];
    int t = threadIdx.x;
    int i = blockIdx.x * 256 + t;
    lds[t] = (i < M) ? hist[i] : 0;
    __syncthreads();
    for (int off = 128; off > 0; off >>= 1) {
        if (t < off) lds[t] += lds[t + off];
        __syncthreads();
    }
    if (t == 0) blockSums[blockIdx.x] = lds[0];
}

__global__ void scan_offsets_kernel(const int* __restrict__ blockSums,
                                    int* __restrict__ blockOffs,
                                    int nB, int* __restrict__ start, int M, int nE) {
    __shared__ int lds[256];
    int t = threadIdx.x;
    int orig = (t < nB) ? blockSums[t] : 0;
    lds[t] = orig;
    __syncthreads();
    for (int off = 1; off < 256; off <<= 1) {
        int v = (t >= off) ? lds[t - off] : 0;
        __syncthreads();
        lds[t] += v;
        __syncthreads();
    }
    if (t < nB) blockOffs[t] = lds[t] - orig;
    if (t == 0) start[M] = nE;
}

__global__ void scan_final_kernel(const int* __restrict__ hist,
                                  const int* __restrict__ blockOffs,
                                  int* __restrict__ start, int M) {
    __shared__ int lds[256];
    int t = threadIdx.x;
    int i = blockIdx.x * 256 + t;
    int orig = (i < M) ? hist[i] : 0;
    lds[t] = orig;
    __syncthreads();
    for (int off = 1; off < 256; off <<= 1) {
        int v = (t >= off) ? lds[t - off] : 0;
        __syncthreads();
        lds[t] += v;
        __syncthreads();
    }
    if (i < M) start[i] = blockOffs[blockIdx.x] + lds[t] - orig;
}

// ---------------- Phase C: bucket-fill src indices ----------------
__global__ void fill_kernel(const int* __restrict__ src, const int* __restrict__ dst,
                            const int* __restrict__ start, int* __restrict__ cursor,
                            int* __restrict__ order, int nE) {
    int e = blockIdx.x * blockDim.x + threadIdx.x;
    if (e >= nE) return;
    int d = dst[e];
    int pos = start[d] + atomicAdd(&cursor[d], 1);
    order[pos] = src[e];
}

// ---------------- prep: xb = bf16(x), weight transposes, pad-row zeroing ----------------
__global__ void prep_kernel(const float* __restrict__ x, unsigned short* __restrict__ xb,
                            const float* __restrict__ W1, const float* __restrict__ W2,
                            const float* __restrict__ Wl,
                            unsigned short* __restrict__ W1t,
                            unsigned short* __restrict__ W2t,
                            unsigned short* __restrict__ Wlt,
                            unsigned short* __restrict__ A1pad,
                            unsigned short* __restrict__ h1pad,
                            int XQ) {
    int idx = blockIdx.x * 256 + threadIdx.x;
    if (idx < XQ) {
        float4 v = ((const float4*)x)[idx];
        ushort4 o;
        o.x = f2bf(v.x); o.y = f2bf(v.y); o.z = f2bf(v.z); o.w = f2bf(v.w);
        ((ushort4*)xb)[idx] = o;
        return;
    }
    int j = idx - XQ;
    if (j < 32768) {                    // W1t: [n=256][k=128]
        int n = j >> 7, k = j & 127;
        W1t[j] = f2bf(W1[k * DIM_H + n]);
    } else if (j < 32768 + 65536) {     // W2t: [n=256][k=256]
        int i = j - 32768;
        int n = i >> 8, k = i & 255;
        W2t[i] = f2bf(W2[k * DIM_H + n]);
    } else if (j < 32768 + 65536 + 16384) {  // Wlt: [n=64][k=256]
        int i = j - 98304;
        int n = i >> 8, k = i & 255;
        Wlt[i] = f2bf((n < N_CLASSES) ? Wl[k * N_CLASSES + n] : 0.f);
    } else if (j < 114688 + 4608) {          // zero pad rows (176 rows worth, ushort4)
        int i = j - 114688;                  // 0..4607
        if (i < 1536) ((ushort4*)A1pad)[i] = make_ushort4(0, 0, 0, 0);   // 48*128/4
        else ((ushort4*)h1pad)[i - 1536] = make_ushort4(0, 0, 0, 0);     // 48*256/4
    }
}

// ---------------- Phase D: gather-reduce (bf16 rows) -> A1 = bf16(x + agg) ----------------
__global__ void gather_agg_kernel(const float* __restrict__ x,
                                  const unsigned short* __restrict__ xb,
                                  const int* __restrict__ order,
                                  const int* __restrict__ start,
                                  unsigned short* __restrict__ A1, int M) {
    int node = blockIdx.x * 8 + (threadIdx.x >> 5);
    if (node >= M) return;
    int lane = threadIdx.x & 31;
    const ushort4* xv = (const ushort4*)xb;
    float4 a0 = ((const float4*)x)[(size_t)node * 32 + lane];  // self term, fp32
    float4 a1 = make_float4(0.f, 0.f, 0.f, 0.f);
    float4 a2 = a1, a3 = a1;
    int e0 = start[node], e1 = start[node + 1];
    int e = e0;
    for (; e + 4 <= e1; e += 4) {
        int s0 = order[e], s1 = order[e + 1], s2 = order[e + 2], s3 = order[e + 3];
        float4 v0 = bf2f4(xv[(size_t)s0 * 32 + lane]);
        float4 v1 = bf2f4(xv[(size_t)s1 * 32 + lane]);
        float4 v2 = bf2f4(xv[(size_t)s2 * 32 + lane]);
        float4 v3 = bf2f4(xv[(size_t)s3 * 32 + lane]);
        a0.x += v0.x; a0.y += v0.y; a0.z += v0.z; a0.w += v0.w;
        a1.x += v1.x; a1.y += v1.y; a1.z += v1.z; a1.w += v1.w;
        a2.x += v2.x; a2.y += v2.y; a2.z += v2.z; a2.w += v2.w;
        a3.x += v3.x; a3.y += v3.y; a3.z += v3.z; a3.w += v3.w;
    }
    for (; e < e1; ++e) {
        float4 v = bf2f4(xv[(size_t)order[e] * 32 + lane]);
        a1.x += v.x; a1.y += v.y; a1.z += v.z; a1.w += v.w;
    }
    float4 t;
    t.x = (a0.x + a1.x) + (a2.x + a3.x);
    t.y = (a0.y + a1.y) + (a2.y + a3.y);
    t.z = (a0.z + a1.z) + (a2.z + a3.z);
    t.w = (a0.w + a1.w) + (a2.w + a3.w);
    ushort4 o;
    o.x = f2bf(t.x); o.y = f2bf(t.y); o.z = f2bf(t.z); o.w = f2bf(t.w);
    ((ushort4*)A1)[(size_t)node * 32 + lane] = o;
}

// ---------------- BN reduce: partials[R][512] -> scale/shift ----------------
__global__ void bn_reduce_kernel(const float* __restrict__ partials, int R,
                                 const float* __restrict__ gamma,
                                 const float* __restrict__ beta,
                                 float* __restrict__ scale,
                                 float* __restrict__ shift, int M) {
    __shared__ float ls[256], lss[256];
    int c = blockIdx.x, t = threadIdx.x;
    float s = 0.f, ss = 0.f;
    for (int r = t; r < R; r += 256) {
        s += partials[(long)r * 512 + c];
        ss += partials[(long)r * 512 + 256 + c];
    }
    ls[t] = s; lss[t] = ss;
    __syncthreads();
    for (int o = 128; o > 0; o >>= 1) {
        if (t < o) { ls[t] += ls[t + o]; lss[t] += lss[t + o]; }
        __syncthreads();
    }
    if (t == 0) {
        float inv = 1.0f / (float)M;
        float mean = ls[0] * inv;
        float var = lss[0] * inv - mean * mean;
        float sc = gamma[c] * rsqrtf(var + BN_EPS);
        scale[c] = sc;
        shift[c] = beta[c] - mean * sc;
    }
}

// ---------------- MFMA GEMM, LDS-staged + double-buffered, full-N tiles ----------------
// WM=1, WN=4: 256 threads, 64x256 tile, grid (1, ceil(M/64)).
// MODE 0: bf16 out + per-block BN column partials (GEMM1)
// MODE 1: BN+ReLU on A during staging; epilogue fuses GEMM3 via LDS h2 tile (GEMM2+3)
template <int WM, int WN, int K, int MODE>
__global__ __launch_bounds__(WM* WN * 64) void mfma_gemm(
    const unsigned short* __restrict__ A,   // [M_PAD, K] bf16 row-major
    const unsigned short* __restrict__ Bt,  // [256, K] bf16 (N-major, K-contig)
    const float* __restrict__ bias,
    void* __restrict__ Cout,
    const float* __restrict__ scale,
    const float* __restrict__ shift,
    float* __restrict__ partials,
    const unsigned short* __restrict__ Wlt2,  // [64,256] bf16 (MODE 1)
    const float* __restrict__ bias2,          // blin (MODE 1)
    int M) {
    constexpr int NT = WM * WN * 64;
    constexpr int BM = WM * 64, BN = WN * 64;
    constexpr int S = K / 32;
    constexpr int PITCH = 40;
    constexpr int ACH = BM * 4 / NT;
    constexpr int BCH = BN * 4 / NT;
    constexpr int STAGE = 2 * (BM + BN) * PITCH;
    constexpr int H2PITCH = 264;
    constexpr int H2T = (MODE == 1) ? BM * H2PITCH : 0;
    constexpr int LDSN = STAGE > H2T ? STAGE : H2T;

    __shared__ __align__(16) unsigned short lds[LDSN];
    unsigned short* AsBase = lds;
    unsigned short* BsBase = lds + 2 * BM * PITCH;

    int tid = threadIdx.x;
    int wave = tid >> 6, lane = tid & 63;
    int wm = wave / WN, wn = wave % WN;
    int l15 = lane & 15, q = lane >> 4;
    long row0 = (long)blockIdx.y * BM;
    long col0 = (long)blockIdx.x * BN;

    bf16x8 ar[ACH], br[BCH];

    auto loadAB = [&](int s) {
#pragma unroll
        for (int i = 0; i < ACH; ++i) {
            int ch = tid + i * NT;
            int m = ch >> 2, c = ch & 3;
            ar[i] = *(const bf16x8*)(A + (row0 + m) * K + s * 32 + c * 8);
        }
#pragma unroll
        for (int i = 0; i < BCH; ++i) {
            int ch = tid + i * NT;
            int m = ch >> 2, c = ch & 3;
            br[i] = *(const bf16x8*)(Bt + (col0 + m) * K + s * 32 + c * 8);
        }
    };

    auto writeAB = [&](int buf, int s) {
#pragma unroll
        for (int i = 0; i < ACH; ++i) {
            int ch = tid + i * NT;
            int m = ch >> 2, c = ch & 3;
            bf16x8 v = ar[i];
            if (MODE == 1) {
                int kb = s * 32 + c * 8;
                float4 sc0 = *(const float4*)(scale + kb);
                float4 sc1 = *(const float4*)(scale + kb + 4);
                float4 sh0 = *(const float4*)(shift + kb);
                float4 sh1 = *(const float4*)(shift + kb + 4);
                float scv[8] = {sc0.x, sc0.y, sc0.z, sc0.w, sc1.x, sc1.y, sc1.z, sc1.w};
                float shv[8] = {sh0.x, sh0.y, sh0.z, sh0.w, sh1.x, sh1.y, sh1.z, sh1.w};
#pragma unroll
                for (int j = 0; j < 8; ++j) {
                    float f = bf2f((unsigned short)v[j]);
                    f = fmaxf(f * scv[j] + shv[j], 0.f);
                    v[j] = (short)f2bf(f);
                }
            }
            *(bf16x8*)(&AsBase[buf * BM * PITCH + m * PITCH + c * 8]) = v;
        }
#pragma unroll
        for (int i = 0; i < BCH; ++i) {
            int ch = tid + i * NT;
            int m = ch >> 2, c = ch & 3;
            *(bf16x8*)(&BsBase[buf * BN * PITCH + m * PITCH + c * 8]) = br[i];
        }
    };

    f32x4 acc[4][4] = {};

    loadAB(0);
    writeAB(0, 0);
#pragma unroll
    for (int s = 0; s < S; ++s) {
        if (s + 1 < S) loadAB(s + 1);
        __syncthreads();
        int buf = s & 1;
        bf16x8 af[4], bfr[4];
#pragma unroll
        for (int mt = 0; mt < 4; ++mt)
            af[mt] = *(const bf16x8*)(&AsBase[buf * BM * PITCH + (wm * 64 + mt * 16 + l15) * PITCH + q * 8]);
#pragma unroll
        for (int nt = 0; nt < 4; ++nt)
            bfr[nt] = *(const bf16x8*)(&BsBase[buf * BN * PITCH + (wn * 64 + nt * 16 + l15) * PITCH + q * 8]);
#pragma unroll
        for (int mt = 0; mt < 4; ++mt)
#pragma unroll
            for (int nt = 0; nt < 4; ++nt)
                acc[mt][nt] = __builtin_amdgcn_mfma_f32_16x16x32_bf16(
                    af[mt], bfr[nt], acc[mt][nt], 0, 0, 0);
        if (s + 1 < S) writeAB((s + 1) & 1, s + 1);
    }

    if (MODE == 0) {
#pragma unroll
        for (int nt = 0; nt < 4; ++nt) {
            long col = col0 + wn * 64 + nt * 16 + l15;
            float b = bias[col];
            float s = 0.f, ss = 0.f;
#pragma unroll
            for (int mt = 0; mt < 4; ++mt) {
#pragma unroll
                for (int r = 0; r < 4; ++r) {
                    long row = row0 + wm * 64 + mt * 16 + q * 4 + r;
                    float v = acc[mt][nt][r] + b;
                    if (row < M) {
                        ((unsigned short*)Cout)[row * DIM_H + col] = f2bf(v);
                        s += v; ss += v * v;
                    }
                }
            }
            s += __shfl_xor(s, 16, 64);  s += __shfl_xor(s, 32, 64);
            ss += __shfl_xor(ss, 16, 64); ss += __shfl_xor(ss, 32, 64);
            if (lane < 16) {
                long pr = (long)blockIdx.y * WM + wm;
                partials[pr * 512 + col] = s;
                partials[pr * 512 + 256 + col] = ss;
            }
        }
    } else {
        __syncthreads();  // staging reads complete; reuse LDS for h2 tile
        unsigned short* h2t = lds;  // [BM][H2PITCH]
#pragma unroll
        for (int nt = 0; nt < 4; ++nt) {
            int colL = wn * 64 + nt * 16 + l15;
            float b = bias[colL];
#pragma unroll
            for (int mt = 0; mt < 4; ++mt)
#pragma unroll
                for (int r = 0; r < 4; ++r) {
                    int rowL = mt * 16 + q * 4 + r;
                    h2t[rowL * H2PITCH + colL] = f2bf(fmaxf(acc[mt][nt][r] + b, 0.f));
                }
        }
        __syncthreads();
        f32x4 acc3[3] = {};
#pragma unroll
        for (int s = 0; s < 8; ++s) {
            bf16x8 a3 = *(const bf16x8*)(&h2t[(wave * 16 + l15) * H2PITCH + s * 32 + q * 8]);
#pragma unroll
            for (int nt = 0; nt < 3; ++nt) {
                bf16x8 b3 = *(const bf16x8*)(Wlt2 + (nt * 16 + l15) * 256 + s * 32 + q * 8);
                acc3[nt] = __builtin_amdgcn_mfma_f32_16x16x32_bf16(a3, b3, acc3[nt], 0, 0, 0);
            }
        }
#pragma unroll
        for (int nt = 0; nt < 3; ++nt) {
            int col = nt * 16 + l15;
            if (col < N_CLASSES) {
                float b = bias2[col];
#pragma unroll
                for (int r = 0; r < 4; ++r) {
                    long row = row0 + wave * 16 + q * 4 + r;
                    if (row < M) ((float*)Cout)[row * N_CLASSES + col] = acc3[nt][r] + b;
                }
            }
        }
    }
}

extern "C" void kernel_launch(void* const* d_in, const int* in_sizes, int n_in,
                              void* d_out, int out_size, void* d_ws, size_t ws_size,
                              hipStream_t stream) {
    const float* x     = (const float*)d_in[0];
    const int*   ei    = (const int*)d_in[1];
    const float* W1    = (const float*)d_in[2];
    const float* b1    = (const float*)d_in[3];
    const float* gamma = (const float*)d_in[4];
    const float* beta  = (const float*)d_in[5];
    const float* W2    = (const float*)d_in[6];
    const float* b2    = (const float*)d_in[7];
    const float* Wlin  = (const float*)d_in[8];
    const float* blin  = (const float*)d_in[9];
    float* out = (float*)d_out;

    int M  = in_sizes[0] / F_IN;  // 50000
    int nE = in_sizes[1] / 2;     // 600000
    const int* srcIdx = ei;
    const int* dstIdx = ei + nE;
    int nB = (M + 255) / 256;
    int gy = (M + 63) / 64;       // 782
    int Rpart = gy;
    int XQ = M * 32;

    unsigned short* A1bf  = (unsigned short*)d_ws;                     // M_PAD*128
    unsigned short* h1bf  = A1bf + (size_t)M_PAD * F_IN;               // M_PAD*256
    unsigned short* xb    = h1bf + (size_t)M_PAD * DIM_H;              // M_PAD*128
    unsigned short* W1t   = xb + (size_t)M_PAD * F_IN;                 // 256*128
    unsigned short* W2t   = W1t + DIM_H * F_IN;                        // 256*256
    unsigned short* Wlt   = W2t + DIM_H * DIM_H;                       // 64*256
    float*          partials = (float*)(Wlt + 64 * DIM_H);             // Rpart*512
    float*          scale = partials + (size_t)800 * 512;              // 256
    float*          shift = scale + DIM_H;                             // 256
    int*            hist  = (int*)(shift + DIM_H);                     // M
    int*            cursor= hist + M;                                  // M
    int*            start = cursor + M;                                // M+1
    int*            blockSums = start + (M + 1);                       // 256
    int*            blockOffs = blockSums + 256;                       // 256
    int*            order = blockOffs + 256;                           // nE

    hipMemsetAsync(hist, 0, (size_t)2 * M * sizeof(int), stream);

    int tB = 256;
    hist_kernel<<<(nE + tB - 1) / tB, tB, 0, stream>>>(dstIdx, hist, nE);
    scan_blocks_kernel<<<nB, 256, 0, stream>>>(hist, blockSums, M);
    scan_offsets_kernel<<<1, 256, 0, stream>>>(blockSums, blockOffs, nB, start, M, nE);
    scan_final_kernel<<<nB, 256, 0, stream>>>(hist, blockOffs, start, M);
    fill_kernel<<<(nE + tB - 1) / tB, tB, 0, stream>>>(srcIdx, dstIdx, start, cursor, order, nE);
    prep_kernel<<<(XQ + 114688 + 4608 + 255) / 256, 256, 0, stream>>>(
        x, xb, W1, W2, Wlin, W1t, W2t, Wlt,
        A1bf + (size_t)M * F_IN, h1bf + (size_t)M * DIM_H, XQ);
    gather_agg_kernel<<<(M + 7) / 8, 256, 0, stream>>>(x, xb, order, start, A1bf, M);

    mfma_gemm<1, 4, F_IN, 0><<<dim3(1, gy), 256, 0, stream>>>(
        A1bf, W1t, b1, h1bf, nullptr, nullptr, partials, nullptr, nullptr, M);
    bn_reduce_kernel<<<DIM_H, 256, 0, stream>>>(partials, Rpart, gamma, beta, scale, shift, M);
    mfma_gemm<1, 4, DIM_H, 1><<<dim3(1, gy), 256, 0, stream>>>(
        h1bf, W2t, b2, out, scale, shift, nullptr, Wlt, blin, M);
}

// Round 9
// 247.540 us; speedup vs baseline: 5.7660x; 1.0178x over previous
//
#include <hip/hip_runtime.h>

#define F_IN 128
#define DIM_H 256
#define N_CLASSES 40
#define BN_EPS 1e-5f
#define M_PAD 50176

typedef short bf16x8 __attribute__((ext_vector_type(8)));
typedef float f32x4 __attribute__((ext_vector_type(4)));

__device__ __forceinline__ unsigned short f2bf(float f) {
    union { float f; unsigned u; } v; v.f = f;
    unsigned r = v.u + 0x7fff + ((v.u >> 16) & 1);  // RNE
    return (unsigned short)(r >> 16);
}
__device__ __forceinline__ float bf2f(unsigned short u) {
    union { unsigned u; float f; } v; v.u = ((unsigned)u) << 16;
    return v.f;
}
__device__ __forceinline__ float4 bf2f4(ushort4 u) {
    return make_float4(bf2f(u.x), bf2f(u.y), bf2f(u.z), bf2f(u.w));
}

// ---------------- Phase A: histogram of dst ----------------
__global__ void hist_kernel(const int* __restrict__ dst, int* __restrict__ hist, int nE) {
    int e = blockIdx.x * blockDim.x + threadIdx.x;
    if (e >= nE) return;
    atomicAdd(&hist[dst[e]], 1);
}

// ---------------- Phase B: hierarchical exclusive scan ----------------
__global__ void scan_blocks_kernel(const int* __restrict__ hist,
                                   int* __restrict__ blockSums, int M) {
    __shared__ int lds[256];
    int t = threadIdx.x;
    int i = blockIdx.x * 256 + t;
    lds[t] = (i < M) ? hist[i] : 0;
    __syncthreads();
    for (int off = 128; off > 0; off >>= 1) {
        if (t < off) lds[t] += lds[t + off];
        __syncthreads();
    }
    if (t == 0) blockSums[blockIdx.x] = lds[0];
}

__global__ void scan_offsets_kernel(const int* __restrict__ blockSums,
                                    int* __restrict__ blockOffs,
                                    int nB, int* __restrict__ start, int M, int nE) {
    __shared__ int lds[256];
    int t = threadIdx.x;
    int orig = (t < nB) ? blockSums[t] : 0;
    lds[t] = orig;
    __syncthreads();
    for (int off = 1; off < 256; off <<= 1) {
        int v = (t >= off) ? lds[t - off] : 0;
        __syncthreads();
        lds[t] += v;
        __syncthreads();
    }
    if (t < nB) blockOffs[t] = lds[t] - orig;
    if (t == 0) start[M] = nE;
}

__global__ void scan_final_kernel(const int* __restrict__ hist,
                                  const int* __restrict__ blockOffs,
                                  int* __restrict__ start, int M) {
    __shared__ int lds[256];
    int t = threadIdx.x;
    int i = blockIdx.x * 256 + t;
    int orig = (i < M) ? hist[i] : 0;
    lds[t] = orig;
    __syncthreads();
    for (int off = 1; off < 256; off <<= 1) {
        int v = (t >= off) ? lds[t - off] : 0;
        __syncthreads();
        lds[t] += v;
        __syncthreads();
    }
    if (i < M) start[i] = blockOffs[blockIdx.x] + lds[t] - orig;
}

// ---------------- Phase C: bucket-fill src indices ----------------
__global__ void fill_kernel(const int* __restrict__ src, const int* __restrict__ dst,
                            const int* __restrict__ start, int* __restrict__ cursor,
                            int* __restrict__ order, int nE) {
    int e = blockIdx.x * blockDim.x + threadIdx.x;
    if (e >= nE) return;
    int d = dst[e];
    int pos = start[d] + atomicAdd(&cursor[d], 1);
    order[pos] = src[e];
}

// ---------------- prep: xb = bf16(x), weight transposes, h1 pad zeroing ----------------
__global__ void prep_kernel(const float* __restrict__ x, unsigned short* __restrict__ xb,
                            const float* __restrict__ W1, const float* __restrict__ W2,
                            const float* __restrict__ Wl,
                            unsigned short* __restrict__ W1t,
                            unsigned short* __restrict__ W2t,
                            unsigned short* __restrict__ Wlt,
                            unsigned short* __restrict__ h1pad,
                            int XQ) {
    int idx = blockIdx.x * 256 + threadIdx.x;
    if (idx < XQ) {
        float4 v = ((const float4*)x)[idx];
        ushort4 o;
        o.x = f2bf(v.x); o.y = f2bf(v.y); o.z = f2bf(v.z); o.w = f2bf(v.w);
        ((ushort4*)xb)[idx] = o;
        return;
    }
    int j = idx - XQ;
    if (j < 32768) {                    // W1t: [n=256][k=128]
        int n = j >> 7, k = j & 127;
        W1t[j] = f2bf(W1[k * DIM_H + n]);
    } else if (j < 32768 + 65536) {     // W2t: [n=256][k=256]
        int i = j - 32768;
        int n = i >> 8, k = i & 255;
        W2t[i] = f2bf(W2[k * DIM_H + n]);
    } else if (j < 32768 + 65536 + 16384) {  // Wlt: [n=64][k=256]
        int i = j - 98304;
        int n = i >> 8, k = i & 255;
        Wlt[i] = f2bf((n < N_CLASSES) ? Wl[k * N_CLASSES + n] : 0.f);
    } else if (j < 114688 + 3072) {          // zero h1 pad rows (48*256 ushorts)
        int i = j - 114688;
        ((ushort4*)h1pad)[i] = make_ushort4(0, 0, 0, 0);
    }
}

// ---------------- BN reduce: partials[R][512] -> scale/shift ----------------
__global__ void bn_reduce_kernel(const float* __restrict__ partials, int R,
                                 const float* __restrict__ gamma,
                                 const float* __restrict__ beta,
                                 float* __restrict__ scale,
                                 float* __restrict__ shift, int M) {
    __shared__ float ls[256], lss[256];
    int c = blockIdx.x, t = threadIdx.x;
    float s = 0.f, ss = 0.f;
    for (int r = t; r < R; r += 256) {
        s += partials[(long)r * 512 + c];
        ss += partials[(long)r * 512 + 256 + c];
    }
    ls[t] = s; lss[t] = ss;
    __syncthreads();
    for (int o = 128; o > 0; o >>= 1) {
        if (t < o) { ls[t] += ls[t + o]; lss[t] += lss[t + o]; }
        __syncthreads();
    }
    if (t == 0) {
        float inv = 1.0f / (float)M;
        float mean = ls[0] * inv;
        float var = lss[0] * inv - mean * mean;
        float sc = gamma[c] * rsqrtf(var + BN_EPS);
        scale[c] = sc;
        shift[c] = beta[c] - mean * sc;
    }
}

// ---------------- fused gather + GEMM1 + BN partials ----------------
// Block: 256 threads = 4 waves, 64-row tile, full N=256.
// Phase 1: gather 64 node rows (x + sum of bf16 neighbor rows) directly into LDS A-tile.
// Phase 2: 4-step K-loop (BK=32) vs W1t, B single-buffered with register prefetch.
// Epilogue: h1 bf16 store + per-block BN column partials.
// LDS 37.9 KB -> 4 blocks/CU -> 1024 resident >= 782 blocks (single generation).
__global__ __launch_bounds__(256, 4) void gin_gemm1_kernel(
    const float* __restrict__ x, const unsigned short* __restrict__ xb,
    const int* __restrict__ order, const int* __restrict__ start,
    const unsigned short* __restrict__ W1t, const float* __restrict__ b1,
    unsigned short* __restrict__ h1, float* __restrict__ partials, int M) {
    constexpr int K = F_IN, S = K / 32;
    constexpr int PA = 136;   // 128 + 8 pad (16B-aligned rows, 2-way free banks)
    constexpr int PB = 40;    // 32 + 8 pad
    __shared__ __align__(16) unsigned short At[64 * PA];   // 17408 B
    __shared__ __align__(16) unsigned short Bs[256 * PB];  // 20480 B

    int tid = threadIdx.x;
    int wave = tid >> 6, lane = tid & 63;
    int l15 = lane & 15, q = lane >> 4;
    int wn = wave;                       // 4 waves tile N
    long row0 = (long)blockIdx.x * 64;

    bf16x8 br[4];
    auto loadB = [&](int s) {
#pragma unroll
        for (int i = 0; i < 4; ++i) {
            int ch = tid + i * 256;
            int m = ch >> 2, c = ch & 3;
            br[i] = *(const bf16x8*)(W1t + m * K + s * 32 + c * 8);
        }
    };
    auto writeB = [&]() {
#pragma unroll
        for (int i = 0; i < 4; ++i) {
            int ch = tid + i * 256;
            int m = ch >> 2, c = ch & 3;
            *(bf16x8*)(&Bs[m * PB + c * 8]) = br[i];
        }
    };

    loadB(0);  // in flight during gather

    // ---- Phase 1: gather into At ----
    {
        int hw = tid >> 5, lane32 = tid & 31;
        const ushort4* xv = (const ushort4*)xb;
        for (int rr = 0; rr < 8; ++rr) {
            int r = rr * 8 + hw;
            long node = row0 + r;
            float4 a0 = make_float4(0.f, 0.f, 0.f, 0.f);
            float4 a1 = a0, a2 = a0, a3 = a0;
            if (node < M) {
                a0 = ((const float4*)x)[node * 32 + lane32];  // self term fp32
                int e0 = start[node], e1 = start[node + 1];
                int e = e0;
                for (; e + 4 <= e1; e += 4) {
                    int s0 = order[e], s1 = order[e + 1], s2 = order[e + 2], s3 = order[e + 3];
                    float4 v0 = bf2f4(xv[(size_t)s0 * 32 + lane32]);
                    float4 v1 = bf2f4(xv[(size_t)s1 * 32 + lane32]);
                    float4 v2 = bf2f4(xv[(size_t)s2 * 32 + lane32]);
                    float4 v3 = bf2f4(xv[(size_t)s3 * 32 + lane32]);
                    a0.x += v0.x; a0.y += v0.y; a0.z += v0.z; a0.w += v0.w;
                    a1.x += v1.x; a1.y += v1.y; a1.z += v1.z; a1.w += v1.w;
                    a2.x += v2.x; a2.y += v2.y; a2.z += v2.z; a2.w += v2.w;
                    a3.x += v3.x; a3.y += v3.y; a3.z += v3.z; a3.w += v3.w;
                }
                for (; e < e1; ++e) {
                    float4 v = bf2f4(xv[(size_t)order[e] * 32 + lane32]);
                    a1.x += v.x; a1.y += v.y; a1.z += v.z; a1.w += v.w;
                }
            }
            float4 t;
            t.x = (a0.x + a1.x) + (a2.x + a3.x);
            t.y = (a0.y + a1.y) + (a2.y + a3.y);
            t.z = (a0.z + a1.z) + (a2.z + a3.z);
            t.w = (a0.w + a1.w) + (a2.w + a3.w);
            ushort4 o;
            o.x = f2bf(t.x); o.y = f2bf(t.y); o.z = f2bf(t.z); o.w = f2bf(t.w);
            *(ushort4*)(&At[r * PA + lane32 * 4]) = o;
        }
    }
    writeB();
    __syncthreads();

    // ---- Phase 2: K-loop ----
    f32x4 acc[4][4] = {};
#pragma unroll
    for (int s = 0; s < S; ++s) {
        if (s + 1 < S) loadB(s + 1);
        bf16x8 af[4], bfr[4];
#pragma unroll
        for (int mt = 0; mt < 4; ++mt)
            af[mt] = *(const bf16x8*)(&At[(mt * 16 + l15) * PA + s * 32 + q * 8]);
#pragma unroll
        for (int nt = 0; nt < 4; ++nt)
            bfr[nt] = *(const bf16x8*)(&Bs[(wn * 64 + nt * 16 + l15) * PB + q * 8]);
#pragma unroll
        for (int mt = 0; mt < 4; ++mt)
#pragma unroll
            for (int nt = 0; nt < 4; ++nt)
                acc[mt][nt] = __builtin_amdgcn_mfma_f32_16x16x32_bf16(
                    af[mt], bfr[nt], acc[mt][nt], 0, 0, 0);
        __syncthreads();
        if (s + 1 < S) { writeB(); __syncthreads(); }
    }

    // ---- Epilogue: h1 + BN partials ----
#pragma unroll
    for (int nt = 0; nt < 4; ++nt) {
        int col = wn * 64 + nt * 16 + l15;
        float b = b1[col];
        float s = 0.f, ss = 0.f;
#pragma unroll
        for (int mt = 0; mt < 4; ++mt) {
#pragma unroll
            for (int r = 0; r < 4; ++r) {
                long row = row0 + mt * 16 + q * 4 + r;
                float v = acc[mt][nt][r] + b;
                if (row < M) {
                    h1[row * DIM_H + col] = f2bf(v);
                    s += v; ss += v * v;
                }
            }
        }
        s += __shfl_xor(s, 16, 64);  s += __shfl_xor(s, 32, 64);
        ss += __shfl_xor(ss, 16, 64); ss += __shfl_xor(ss, 32, 64);
        if (lane < 16) {
            partials[(long)blockIdx.x * 512 + col] = s;
            partials[(long)blockIdx.x * 512 + 256 + col] = ss;
        }
    }
}

// ---------------- fused GEMM2 + GEMM3 ----------------
// BN+ReLU on A at staging; A and B single-buffered (reg prefetch, 2 barriers/step);
// epilogue: relu(h2)->LDS tile (aliased) -> h2 @ Wlt + blin -> out.
// LDS 33.8 KB -> 4 blocks/CU -> single generation.
__global__ __launch_bounds__(256, 4) void gemm23_kernel(
    const unsigned short* __restrict__ h1, const unsigned short* __restrict__ W2t,
    const float* __restrict__ b2,
    const float* __restrict__ scale, const float* __restrict__ shift,
    const unsigned short* __restrict__ Wlt, const float* __restrict__ blin,
    float* __restrict__ out, int M) {
    constexpr int K = DIM_H, S = K / 32;
    constexpr int PA = 40;     // A step-tile pitch
    constexpr int PB = 40;
    constexpr int PH = 264;    // h2 tile pitch (256 + 8)
    constexpr int LDSN = 64 * PH;  // 16896 ushorts = 33792 B (>= As+Bs = 12800)
    __shared__ __align__(16) unsigned short lds[LDSN];
    unsigned short* As = lds;              // [64][PA]
    unsigned short* Bs = lds + 64 * PA;    // [256][PB]
    unsigned short* h2t = lds;             // [64][PH] (alias, used after K-loop)

    int tid = threadIdx.x;
    int wave = tid >> 6, lane = tid & 63;
    int l15 = lane & 15, q = lane >> 4;
    int wn = wave;
    long row0 = (long)blockIdx.x * 64;

    bf16x8 ar, br[4];
    auto loadAB = [&](int s) {
        {   // A: 1 chunk/thread
            int m = tid >> 2, c = tid & 3;
            ar = *(const bf16x8*)(h1 + (row0 + m) * K + s * 32 + c * 8);
        }
#pragma unroll
        for (int i = 0; i < 4; ++i) {
            int ch = tid + i * 256;
            int m = ch >> 2, c = ch & 3;
            br[i] = *(const bf16x8*)(W2t + m * K + s * 32 + c * 8);
        }
    };
    auto writeAB = [&](int s) {
        {
            int m = tid >> 2, c = tid & 3;
            int kb = s * 32 + c * 8;
            float4 sc0 = *(const float4*)(scale + kb);
            float4 sc1 = *(const float4*)(scale + kb + 4);
            float4 sh0 = *(const float4*)(shift + kb);
            float4 sh1 = *(const float4*)(shift + kb + 4);
            float scv[8] = {sc0.x, sc0.y, sc0.z, sc0.w, sc1.x, sc1.y, sc1.z, sc1.w};
            float shv[8] = {sh0.x, sh0.y, sh0.z, sh0.w, sh1.x, sh1.y, sh1.z, sh1.w};
            bf16x8 v = ar;
#pragma unroll
            for (int j = 0; j < 8; ++j) {
                float f = bf2f((unsigned short)v[j]);
                f = fmaxf(f * scv[j] + shv[j], 0.f);
                v[j] = (short)f2bf(f);
            }
            *(bf16x8*)(&As[m * PA + c * 8]) = v;
        }
#pragma unroll
        for (int i = 0; i < 4; ++i) {
            int ch = tid + i * 256;
            int m = ch >> 2, c = ch & 3;
            *(bf16x8*)(&Bs[m * PB + c * 8]) = br[i];
        }
    };

    f32x4 acc[4][4] = {};

    loadAB(0);
    writeAB(0);
    __syncthreads();
#pragma unroll
    for (int s = 0; s < S; ++s) {
        if (s + 1 < S) loadAB(s + 1);
        bf16x8 af[4], bfr[4];
#pragma unroll
        for (int mt = 0; mt < 4; ++mt)
            af[mt] = *(const bf16x8*)(&As[(mt * 16 + l15) * PA + q * 8]);
#pragma unroll
        for (int nt = 0; nt < 4; ++nt)
            bfr[nt] = *(const bf16x8*)(&Bs[(wn * 64 + nt * 16 + l15) * PB + q * 8]);
#pragma unroll
        for (int mt = 0; mt < 4; ++mt)
#pragma unroll
            for (int nt = 0; nt < 4; ++nt)
                acc[mt][nt] = __builtin_amdgcn_mfma_f32_16x16x32_bf16(
                    af[mt], bfr[nt], acc[mt][nt], 0, 0, 0);
        __syncthreads();
        if (s + 1 < S) { writeAB(s + 1); __syncthreads(); }
    }

    // ---- h2 tile -> LDS (alias) ----
#pragma unroll
    for (int nt = 0; nt < 4; ++nt) {
        int colL = wn * 64 + nt * 16 + l15;
        float b = b2[colL];
#pragma unroll
        for (int mt = 0; mt < 4; ++mt)
#pragma unroll
            for (int r = 0; r < 4; ++r) {
                int rowL = mt * 16 + q * 4 + r;
                h2t[rowL * PH + colL] = f2bf(fmaxf(acc[mt][nt][r] + b, 0.f));
            }
    }
    __syncthreads();

    // ---- GEMM3: each wave 16 rows x 48 cols, K=256 ----
    f32x4 acc3[3] = {};
#pragma unroll
    for (int s = 0; s < 8; ++s) {
        bf16x8 a3 = *(const bf16x8*)(&h2t[(wave * 16 + l15) * PH + s * 32 + q * 8]);
#pragma unroll
        for (int nt = 0; nt < 3; ++nt) {
            bf16x8 b3 = *(const bf16x8*)(Wlt + (nt * 16 + l15) * 256 + s * 32 + q * 8);
            acc3[nt] = __builtin_amdgcn_mfma_f32_16x16x32_bf16(a3, b3, acc3[nt], 0, 0, 0);
        }
    }
#pragma unroll
    for (int nt = 0; nt < 3; ++nt) {
        int col = nt * 16 + l15;
        if (col < N_CLASSES) {
            float b = blin[col];
#pragma unroll
            for (int r = 0; r < 4; ++r) {
                long row = row0 + wave * 16 + q * 4 + r;
                if (row < M) out[row * N_CLASSES + col] = acc3[nt][r] + b;
            }
        }
    }
}

extern "C" void kernel_launch(void* const* d_in, const int* in_sizes, int n_in,
                              void* d_out, int out_size, void* d_ws, size_t ws_size,
                              hipStream_t stream) {
    const float* x     = (const float*)d_in[0];
    const int*   ei    = (const int*)d_in[1];
    const float* W1    = (const float*)d_in[2];
    const float* b1    = (const float*)d_in[3];
    const float* gamma = (const float*)d_in[4];
    const float* beta  = (const float*)d_in[5];
    const float* W2    = (const float*)d_in[6];
    const float* b2    = (const float*)d_in[7];
    const float* Wlin  = (const float*)d_in[8];
    const float* blin  = (const float*)d_in[9];
    float* out = (float*)d_out;

    int M  = in_sizes[0] / F_IN;  // 50000
    int nE = in_sizes[1] / 2;     // 600000
    const int* srcIdx = ei;
    const int* dstIdx = ei + nE;
    int nB = (M + 255) / 256;
    int gy = (M + 63) / 64;       // 782
    int XQ = M * 32;

    unsigned short* h1bf  = (unsigned short*)d_ws;                     // M_PAD*256
    unsigned short* xb    = h1bf + (size_t)M_PAD * DIM_H;              // M_PAD*128
    unsigned short* W1t   = xb + (size_t)M_PAD * F_IN;                 // 256*128
    unsigned short* W2t   = W1t + DIM_H * F_IN;                        // 256*256
    unsigned short* Wlt   = W2t + DIM_H * DIM_H;                       // 64*256
    float*          partials = (float*)(Wlt + 64 * DIM_H);             // gy*512
    float*          scale = partials + (size_t)800 * 512;              // 256
    float*          shift = scale + DIM_H;                             // 256
    int*            hist  = (int*)(shift + DIM_H);                     // M
    int*            cursor= hist + M;                                  // M
    int*            start = cursor + M;                                // M+1
    int*            blockSums = start + (M + 1);                       // 256
    int*            blockOffs = blockSums + 256;                       // 256
    int*            order = blockOffs + 256;                           // nE

    hipMemsetAsync(hist, 0, (size_t)2 * M * sizeof(int), stream);  // hist + cursor

    int tB = 256;
    hist_kernel<<<(nE + tB - 1) / tB, tB, 0, stream>>>(dstIdx, hist, nE);
    scan_blocks_kernel<<<nB, 256, 0, stream>>>(hist, blockSums, M);
    scan_offsets_kernel<<<1, 256, 0, stream>>>(blockSums, blockOffs, nB, start, M, nE);
    scan_final_kernel<<<nB, 256, 0, stream>>>(hist, blockOffs, start, M);
    fill_kernel<<<(nE + tB - 1) / tB, tB, 0, stream>>>(srcIdx, dstIdx, start, cursor, order, nE);
    prep_kernel<<<(XQ + 114688 + 3072 + 255) / 256, 256, 0, stream>>>(
        x, xb, W1, W2, Wlin, W1t, W2t, Wlt, h1bf + (size_t)M * DIM_H, XQ);

    // fused gather + GEMM1 + BN partials
    gin_gemm1_kernel<<<gy, 256, 0, stream>>>(x, xb, order, start, W1t, b1, h1bf, partials, M);
    bn_reduce_kernel<<<DIM_H, 256, 0, stream>>>(partials, gy, gamma, beta, scale, shift, M);
    // fused GEMM2 + GEMM3
    gemm23_kernel<<<gy, 256, 0, stream>>>(h1bf, W2t, b2, scale, shift, Wlt, blin, out, M);
}

// Round 10
// 241.537 us; speedup vs baseline: 5.9093x; 1.0249x over previous
//
#include <hip/hip_runtime.h>

#define F_IN 128
#define DIM_H 256
#define N_CLASSES 40
#define BN_EPS 1e-5f
#define M_PAD 50176

typedef short bf16x8 __attribute__((ext_vector_type(8)));
typedef float f32x4 __attribute__((ext_vector_type(4)));

__device__ __forceinline__ unsigned short f2bf(float f) {
    union { float f; unsigned u; } v; v.f = f;
    unsigned r = v.u + 0x7fff + ((v.u >> 16) & 1);  // RNE
    return (unsigned short)(r >> 16);
}
__device__ __forceinline__ float bf2f(unsigned short u) {
    union { unsigned u; float f; } v; v.u = ((unsigned)u) << 16;
    return v.f;
}
__device__ __forceinline__ float4 bf2f4(ushort4 u) {
    return make_float4(bf2f(u.x), bf2f(u.y), bf2f(u.z), bf2f(u.w));
}

// ---------------- Phase A: histogram of dst ----------------
__global__ void hist_kernel(const int* __restrict__ dst, int* __restrict__ hist, int nE) {
    int e = blockIdx.x * blockDim.x + threadIdx.x;
    if (e >= nE) return;
    atomicAdd(&hist[dst[e]], 1);
}

// ---------------- Phase B: scan (2 kernels; scan_final self-computes its offset) ----------------
__global__ void scan_blocks_kernel(const int* __restrict__ hist,
                                   int* __restrict__ blockSums, int M) {
    __shared__ int lds[256];
    int t = threadIdx.x;
    int i = blockIdx.x * 256 + t;
    lds[t] = (i < M) ? hist[i] : 0;
    __syncthreads();
    for (int off = 128; off > 0; off >>= 1) {
        if (t < off) lds[t] += lds[t + off];
        __syncthreads();
    }
    if (t == 0) blockSums[blockIdx.x] = lds[0];
}

__global__ void scan_final_kernel(const int* __restrict__ hist,
                                  const int* __restrict__ blockSums,
                                  int* __restrict__ start, int M, int nE) {
    __shared__ int lds[256];
    int t = threadIdx.x;
    // block offset = sum of blockSums[0 .. blockIdx.x-1]
    lds[t] = (t < blockIdx.x) ? blockSums[t] : 0;
    __syncthreads();
    for (int o = 128; o > 0; o >>= 1) {
        if (t < o) lds[t] += lds[t + o];
        __syncthreads();
    }
    int off = lds[0];
    __syncthreads();
    // intra-block exclusive scan
    int i = blockIdx.x * 256 + t;
    int orig = (i < M) ? hist[i] : 0;
    lds[t] = orig;
    __syncthreads();
    for (int o = 1; o < 256; o <<= 1) {
        int v = (t >= o) ? lds[t - o] : 0;
        __syncthreads();
        lds[t] += v;
        __syncthreads();
    }
    if (i < M) start[i] = off + lds[t] - orig;
    if (blockIdx.x == 0 && t == 0) start[M] = nE;
}

// ---------------- Phase C: bucket-fill src indices ----------------
__global__ void fill_kernel(const int* __restrict__ src, const int* __restrict__ dst,
                            const int* __restrict__ start, int* __restrict__ cursor,
                            int* __restrict__ order, int nE) {
    int e = blockIdx.x * blockDim.x + threadIdx.x;
    if (e >= nE) return;
    int d = dst[e];
    int pos = start[d] + atomicAdd(&cursor[d], 1);
    order[pos] = src[e];
}

// ---------------- prep: xb = bf16(x), weight transposes, hist+cursor zeroing ----------------
__global__ void prep_kernel(const float* __restrict__ x, unsigned short* __restrict__ xb,
                            const float* __restrict__ W1, const float* __restrict__ W2,
                            const float* __restrict__ Wl,
                            unsigned short* __restrict__ W1t,
                            unsigned short* __restrict__ W2t,
                            unsigned short* __restrict__ Wlt,
                            int* __restrict__ histz,   // hist (cursor adjacent), 2*M ints
                            int XQ, int ZQ) {
    int idx = blockIdx.x * 256 + threadIdx.x;
    if (idx < XQ) {
        float4 v = ((const float4*)x)[idx];
        ushort4 o;
        o.x = f2bf(v.x); o.y = f2bf(v.y); o.z = f2bf(v.z); o.w = f2bf(v.w);
        ((ushort4*)xb)[idx] = o;
        return;
    }
    int j = idx - XQ;
    if (j < 32768) {                    // W1t: [n=256][k=128]
        int n = j >> 7, k = j & 127;
        W1t[j] = f2bf(W1[k * DIM_H + n]);
    } else if (j < 32768 + 65536) {     // W2t: [n=256][k=256]
        int i = j - 32768;
        int n = i >> 8, k = i & 255;
        W2t[i] = f2bf(W2[k * DIM_H + n]);
    } else if (j < 32768 + 65536 + 16384) {  // Wlt: [n=64][k=256]
        int i = j - 98304;
        int n = i >> 8, k = i & 255;
        Wlt[i] = f2bf((n < N_CLASSES) ? Wl[k * N_CLASSES + n] : 0.f);
    } else if (j < 114688 + 0 + 1) {
        // placeholder branch to keep constants readable
    }
    int z = j - 114688;
    if (z >= 0 && z < ZQ) {             // zero hist + cursor (2*M ints, int4)
        ((int4*)histz)[z] = make_int4(0, 0, 0, 0);
    }
}

// ---------------- BN reduce: partials[R][512] -> scale/shift ----------------
__global__ void bn_reduce_kernel(const float* __restrict__ partials, int R,
                                 const float* __restrict__ gamma,
                                 const float* __restrict__ beta,
                                 float* __restrict__ scale,
                                 float* __restrict__ shift, int M) {
    __shared__ float ls[256], lss[256];
    int c = blockIdx.x, t = threadIdx.x;
    float s = 0.f, ss = 0.f;
    for (int r = t; r < R; r += 256) {
        s += partials[(long)r * 512 + c];
        ss += partials[(long)r * 512 + 256 + c];
    }
    ls[t] = s; lss[t] = ss;
    __syncthreads();
    for (int o = 128; o > 0; o >>= 1) {
        if (t < o) { ls[t] += ls[t + o]; lss[t] += lss[t + o]; }
        __syncthreads();
    }
    if (t == 0) {
        float inv = 1.0f / (float)M;
        float mean = ls[0] * inv;
        float var = lss[0] * inv - mean * mean;
        float sc = gamma[c] * rsqrtf(var + BN_EPS);
        scale[c] = sc;
        shift[c] = beta[c] - mean * sc;
    }
}

// ---------------- fused gather + GEMM1 + BN partials ----------------
// 64-row tile, 4 waves. Gather (bf16 self + neighbors) -> LDS A-tile; 4-step K-loop vs W1t;
// epilogue: BN partials + h1 staged through LDS for contiguous 16B/thread stores.
// LDS 37.9 KB -> 4 blocks/CU (single generation at 782 blocks).
__global__ __launch_bounds__(256, 4) void gin_gemm1_kernel(
    const unsigned short* __restrict__ xb,
    const int* __restrict__ order, const int* __restrict__ start,
    const unsigned short* __restrict__ W1t, const float* __restrict__ b1,
    unsigned short* __restrict__ h1, float* __restrict__ partials, int M) {
    constexpr int K = F_IN, S = K / 32;
    constexpr int PA = 136;   // 128 + 8
    constexpr int PB = 40;    // 32 + 8
    constexpr int PH = 264;   // 256 + 8 (h1 staging alias)
    __shared__ __align__(16) unsigned short lds[64 * PA + 256 * PB];  // 18944 ush = 37888 B
    unsigned short* At = lds;
    unsigned short* Bs = lds + 64 * PA;
    unsigned short* h1t = lds;  // 64*264 = 16896 ush <= 18944  (alias after K-loop)

    int tid = threadIdx.x;
    int wave = tid >> 6, lane = tid & 63;
    int l15 = lane & 15, q = lane >> 4;
    int wn = wave;
    long row0 = (long)blockIdx.x * 64;

    bf16x8 br[4];
    auto loadB = [&](int s) {
#pragma unroll
        for (int i = 0; i < 4; ++i) {
            int ch = tid + i * 256;
            int m = ch >> 2, c = ch & 3;
            br[i] = *(const bf16x8*)(W1t + m * K + s * 32 + c * 8);
        }
    };
    auto writeB = [&]() {
#pragma unroll
        for (int i = 0; i < 4; ++i) {
            int ch = tid + i * 256;
            int m = ch >> 2, c = ch & 3;
            *(bf16x8*)(&Bs[m * PB + c * 8]) = br[i];
        }
    };

    loadB(0);  // in flight during gather

    // ---- Phase 1: gather into At (bf16 self term) ----
    {
        int hw = tid >> 5, lane32 = tid & 31;
        const ushort4* xv = (const ushort4*)xb;
        for (int rr = 0; rr < 8; ++rr) {
            int r = rr * 8 + hw;
            long node = row0 + r;
            float4 a0 = make_float4(0.f, 0.f, 0.f, 0.f);
            float4 a1 = a0, a2 = a0, a3 = a0;
            if (node < M) {
                a0 = bf2f4(xv[node * 32 + lane32]);  // self term
                int e0 = start[node], e1 = start[node + 1];
                int e = e0;
                for (; e + 4 <= e1; e += 4) {
                    int s0 = order[e], s1 = order[e + 1], s2 = order[e + 2], s3 = order[e + 3];
                    float4 v0 = bf2f4(xv[(size_t)s0 * 32 + lane32]);
                    float4 v1 = bf2f4(xv[(size_t)s1 * 32 + lane32]);
                    float4 v2 = bf2f4(xv[(size_t)s2 * 32 + lane32]);
                    float4 v3 = bf2f4(xv[(size_t)s3 * 32 + lane32]);
                    a0.x += v0.x; a0.y += v0.y; a0.z += v0.z; a0.w += v0.w;
                    a1.x += v1.x; a1.y += v1.y; a1.z += v1.z; a1.w += v1.w;
                    a2.x += v2.x; a2.y += v2.y; a2.z += v2.z; a2.w += v2.w;
                    a3.x += v3.x; a3.y += v3.y; a3.z += v3.z; a3.w += v3.w;
                }
                for (; e < e1; ++e) {
                    float4 v = bf2f4(xv[(size_t)order[e] * 32 + lane32]);
                    a1.x += v.x; a1.y += v.y; a1.z += v.z; a1.w += v.w;
                }
            }
            float4 t;
            t.x = (a0.x + a1.x) + (a2.x + a3.x);
            t.y = (a0.y + a1.y) + (a2.y + a3.y);
            t.z = (a0.z + a1.z) + (a2.z + a3.z);
            t.w = (a0.w + a1.w) + (a2.w + a3.w);
            ushort4 o;
            o.x = f2bf(t.x); o.y = f2bf(t.y); o.z = f2bf(t.z); o.w = f2bf(t.w);
            *(ushort4*)(&At[r * PA + lane32 * 4]) = o;
        }
    }
    writeB();
    __syncthreads();

    // ---- Phase 2: K-loop ----
    f32x4 acc[4][4] = {};
#pragma unroll
    for (int s = 0; s < S; ++s) {
        if (s + 1 < S) loadB(s + 1);
        bf16x8 af[4], bfr[4];
#pragma unroll
        for (int mt = 0; mt < 4; ++mt)
            af[mt] = *(const bf16x8*)(&At[(mt * 16 + l15) * PA + s * 32 + q * 8]);
#pragma unroll
        for (int nt = 0; nt < 4; ++nt)
            bfr[nt] = *(const bf16x8*)(&Bs[(wn * 64 + nt * 16 + l15) * PB + q * 8]);
#pragma unroll
        for (int mt = 0; mt < 4; ++mt)
#pragma unroll
            for (int nt = 0; nt < 4; ++nt)
                acc[mt][nt] = __builtin_amdgcn_mfma_f32_16x16x32_bf16(
                    af[mt], bfr[nt], acc[mt][nt], 0, 0, 0);
        __syncthreads();
        if (s + 1 < S) { writeB(); __syncthreads(); }
    }
    // all waves past final barrier: At/Bs dead, safe to alias h1t

    // ---- Epilogue: BN partials (fp32, pre-round) + staged h1 tile ----
#pragma unroll
    for (int nt = 0; nt < 4; ++nt) {
        int col = wn * 64 + nt * 16 + l15;
        float b = b1[col];
        float s = 0.f, ss = 0.f;
#pragma unroll
        for (int mt = 0; mt < 4; ++mt) {
#pragma unroll
            for (int r = 0; r < 4; ++r) {
                long row = row0 + mt * 16 + q * 4 + r;
                float v = acc[mt][nt][r] + b;
                if (row < M) { s += v; ss += v * v; }
                h1t[(mt * 16 + q * 4 + r) * PH + col] = f2bf(v);
            }
        }
        s += __shfl_xor(s, 16, 64);  s += __shfl_xor(s, 32, 64);
        ss += __shfl_xor(ss, 16, 64); ss += __shfl_xor(ss, 32, 64);
        if (lane < 16) {
            partials[(long)blockIdx.x * 512 + col] = s;
            partials[(long)blockIdx.x * 512 + 256 + col] = ss;
        }
    }
    __syncthreads();
    // contiguous stores: thread t covers row t>>2, 64-col segment (t&3)*64
    {
        int srow = tid >> 2, scol = (tid & 3) * 64;
        unsigned short* dst = h1 + (row0 + srow) * DIM_H + scol;
        const unsigned short* srcp = &h1t[srow * PH + scol];
#pragma unroll
        for (int j = 0; j < 8; ++j)
            *(bf16x8*)(dst + j * 8) = *(const bf16x8*)(srcp + j * 8);
    }
}

// ---------------- fused GEMM2 + GEMM3, 128x256 tile, 512 threads ----------------
// Double-buffered staging (1 barrier/step); BN+ReLU on A at staging; epilogue:
// relu(h2)->LDS h2 tile (aliases both stage buffers) -> @ Wlt + blin -> out.
// LDS 67.6 KB -> 2 blocks/CU; grid 391 <= 512 resident (single generation).
__global__ __launch_bounds__(512, 4) void gemm23_kernel(
    const unsigned short* __restrict__ h1, const unsigned short* __restrict__ W2t,
    const float* __restrict__ b2,
    const float* __restrict__ scale, const float* __restrict__ shift,
    const unsigned short* __restrict__ Wlt, const float* __restrict__ blin,
    float* __restrict__ out, int M) {
    constexpr int S = 8;
    constexpr int PA = 40, PB = 40, PH = 264;
    constexpr int STAGE = 128 * PA + 256 * PB;        // 15360 ushorts per buffer
    __shared__ __align__(16) unsigned short lds[128 * PH];  // 33792 ush = 67584 B >= 2*STAGE
    unsigned short* h2t = lds;

    int tid = threadIdx.x;
    int wave = tid >> 6, lane = tid & 63;
    int wm = wave >> 2, wn = wave & 3;   // 2 x 4 wave grid
    int l15 = lane & 15, q = lane >> 4;
    long row0 = (long)blockIdx.x * 128;

    int am = tid >> 2, ac = tid & 3;     // A chunk coords (128 rows x 4 chunks)
    bf16x8 ar, br[2];
    auto loadAB = [&](int s) {
        ar = *(const bf16x8*)(h1 + (row0 + am) * DIM_H + s * 32 + ac * 8);
#pragma unroll
        for (int i = 0; i < 2; ++i) {
            int ch = tid + i * 512;
            int m = ch >> 2, c = ch & 3;
            br[i] = *(const bf16x8*)(W2t + m * DIM_H + s * 32 + c * 8);
        }
    };
    auto writeAB = [&](int s, int buf) {
        unsigned short* As = lds + buf * STAGE;
        unsigned short* Bs = As + 128 * PA;
        {
            int kb = s * 32 + ac * 8;
            float4 sc0 = *(const float4*)(scale + kb);
            float4 sc1 = *(const float4*)(scale + kb + 4);
            float4 sh0 = *(const float4*)(shift + kb);
            float4 sh1 = *(const float4*)(shift + kb + 4);
            float scv[8] = {sc0.x, sc0.y, sc0.z, sc0.w, sc1.x, sc1.y, sc1.z, sc1.w};
            float shv[8] = {sh0.x, sh0.y, sh0.z, sh0.w, sh1.x, sh1.y, sh1.z, sh1.w};
            bf16x8 v = ar;
#pragma unroll
            for (int j = 0; j < 8; ++j) {
                float f = bf2f((unsigned short)v[j]);
                f = fmaxf(f * scv[j] + shv[j], 0.f);
                v[j] = (short)f2bf(f);
            }
            *(bf16x8*)(&As[am * PA + ac * 8]) = v;
        }
#pragma unroll
        for (int i = 0; i < 2; ++i) {
            int ch = tid + i * 512;
            int m = ch >> 2, c = ch & 3;
            *(bf16x8*)(&Bs[m * PB + c * 8]) = br[i];
        }
    };

    f32x4 acc[4][4] = {};
    loadAB(0);
    writeAB(0, 0);
#pragma unroll
    for (int s = 0; s < S; ++s) {
        if (s + 1 < S) loadAB(s + 1);
        __syncthreads();  // publish buffer s&1
        const unsigned short* As = lds + (s & 1) * STAGE;
        const unsigned short* Bs = As + 128 * PA;
        bf16x8 af[4], bfr[4];
#pragma unroll
        for (int mt = 0; mt < 4; ++mt)
            af[mt] = *(const bf16x8*)(&As[(wm * 64 + mt * 16 + l15) * PA + q * 8]);
#pragma unroll
        for (int nt = 0; nt < 4; ++nt)
            bfr[nt] = *(const bf16x8*)(&Bs[(wn * 64 + nt * 16 + l15) * PB + q * 8]);
#pragma unroll
        for (int mt = 0; mt < 4; ++mt)
#pragma unroll
            for (int nt = 0; nt < 4; ++nt)
                acc[mt][nt] = __builtin_amdgcn_mfma_f32_16x16x32_bf16(
                    af[mt], bfr[nt], acc[mt][nt], 0, 0, 0);
        if (s + 1 < S) writeAB(s + 1, (s + 1) & 1);  // other buffer: safe, published next barrier
    }
    __syncthreads();  // all MFMA LDS reads done before h2t alias writes

    // ---- h2 tile -> LDS ----
#pragma unroll
    for (int nt = 0; nt < 4; ++nt) {
        int colL = wn * 64 + nt * 16 + l15;
        float b = b2[colL];
#pragma unroll
        for (int mt = 0; mt < 4; ++mt)
#pragma unroll
            for (int r = 0; r < 4; ++r) {
                int rowL = wm * 64 + mt * 16 + q * 4 + r;
                h2t[rowL * PH + colL] = f2bf(fmaxf(acc[mt][nt][r] + b, 0.f));
            }
    }
    __syncthreads();

    // ---- GEMM3: each wave 16 rows x 48 cols, K=256 ----
    f32x4 acc3[3] = {};
#pragma unroll
    for (int s = 0; s < 8; ++s) {
        bf16x8 a3 = *(const bf16x8*)(&h2t[(wave * 16 + l15) * PH + s * 32 + q * 8]);
#pragma unroll
        for (int nt = 0; nt < 3; ++nt) {
            bf16x8 b3 = *(const bf16x8*)(Wlt + (nt * 16 + l15) * 256 + s * 32 + q * 8);
            acc3[nt] = __builtin_amdgcn_mfma_f32_16x16x32_bf16(a3, b3, acc3[nt], 0, 0, 0);
        }
    }
#pragma unroll
    for (int nt = 0; nt < 3; ++nt) {
        int col = nt * 16 + l15;
        if (col < N_CLASSES) {
            float b = blin[col];
#pragma unroll
            for (int r = 0; r < 4; ++r) {
                long row = row0 + wave * 16 + q * 4 + r;
                if (row < M) out[row * N_CLASSES + col] = acc3[nt][r] + b;
            }
        }
    }
}

extern "C" void kernel_launch(void* const* d_in, const int* in_sizes, int n_in,
                              void* d_out, int out_size, void* d_ws, size_t ws_size,
                              hipStream_t stream) {
    const float* x     = (const float*)d_in[0];
    const int*   ei    = (const int*)d_in[1];
    const float* W1    = (const float*)d_in[2];
    const float* b1    = (const float*)d_in[3];
    const float* gamma = (const float*)d_in[4];
    const float* beta  = (const float*)d_in[5];
    const float* W2    = (const float*)d_in[6];
    const float* b2    = (const float*)d_in[7];
    const float* Wlin  = (const float*)d_in[8];
    const float* blin  = (const float*)d_in[9];
    float* out = (float*)d_out;

    int M  = in_sizes[0] / F_IN;  // 50000
    int nE = in_sizes[1] / 2;     // 600000
    const int* srcIdx = ei;
    const int* dstIdx = ei + nE;
    int nB = (M + 255) / 256;     // 196
    int gy1 = (M + 63) / 64;      // 782
    int gy23 = (M + 127) / 128;   // 391
    int XQ = M * 32;              // x float4-quads
    int ZQ = 2 * M / 4;           // hist+cursor int4 zero jobs (25000)

    unsigned short* h1bf  = (unsigned short*)d_ws;                     // M_PAD*256
    unsigned short* xb    = h1bf + (size_t)M_PAD * DIM_H;              // M_PAD*128
    unsigned short* W1t   = xb + (size_t)M_PAD * F_IN;                 // 256*128
    unsigned short* W2t   = W1t + DIM_H * F_IN;                        // 256*256
    unsigned short* Wlt   = W2t + DIM_H * DIM_H;                       // 64*256
    float*          partials = (float*)(Wlt + 64 * DIM_H);             // gy1*512
    float*          scale = partials + (size_t)800 * 512;              // 256
    float*          shift = scale + DIM_H;                             // 256
    int*            hist  = (int*)(shift + DIM_H);                     // M
    int*            cursor= hist + M;                                  // M (adjacent)
    int*            start = cursor + M;                                // M+1
    int*            blockSums = start + (M + 1);                       // 256
    int*            order = blockSums + 256;                           // nE

    int tB = 256;
    // prep first: zeroes hist+cursor, builds xb + transposed weights
    prep_kernel<<<(XQ + 114688 + ZQ + 255) / 256, 256, 0, stream>>>(
        x, xb, W1, W2, Wlin, W1t, W2t, Wlt, hist, XQ, ZQ);
    hist_kernel<<<(nE + tB - 1) / tB, tB, 0, stream>>>(dstIdx, hist, nE);
    scan_blocks_kernel<<<nB, 256, 0, stream>>>(hist, blockSums, M);
    scan_final_kernel<<<nB, 256, 0, stream>>>(hist, blockSums, start, M, nE);
    fill_kernel<<<(nE + tB - 1) / tB, tB, 0, stream>>>(srcIdx, dstIdx, start, cursor, order, nE);

    // fused gather + GEMM1 + BN partials
    gin_gemm1_kernel<<<gy1, 256, 0, stream>>>(xb, order, start, W1t, b1, h1bf, partials, M);
    bn_reduce_kernel<<<DIM_H, 256, 0, stream>>>(partials, gy1, gamma, beta, scale, shift, M);
    // fused GEMM2 + GEMM3 (128-row tiles, double-buffered)
    gemm23_kernel<<<gy23, 512, 0, stream>>>(h1bf, W2t, b2, scale, shift, Wlt, blin, out, M);
}